// Round 6
// baseline (148.093 us; speedup 1.0000x reference)
//
#include <hip/hip_runtime.h>
#include <math.h>

#define B_    64
#define QLEN  32
#define DLEN  2048
#define WORD  300
#define ENT   128
#define AD    256
#define NK    11
#define KDIM  428
#define VOCAB 50000
#define BM    128          // docs per block (fused kernel)

typedef __bf16 bf16x8 __attribute__((ext_vector_type(8)));
typedef __bf16 bf16x4 __attribute__((ext_vector_type(4)));
typedef float  f32x4  __attribute__((ext_vector_type(4)));

static __device__ const float d_mus[NK] =
    {-0.9f,-0.7f,-0.5f,-0.3f,-0.1f,0.1f,0.3f,0.5f,0.7f,0.9f,1.0f};
static __device__ const float d_coef[NK] =
    {-50.f,-50.f,-50.f,-50.f,-50.f,-50.f,-50.f,-50.f,-50.f,-50.f,-500000.f};

// ---------------------------------------------------------------------------
// W-pack: Wtp (K=320 pad, 160 tiles) and Wep (K=128, 64 tiles) in B-frag
// order; tile = 64 lanes x 16B; lane l elem j: B[k=s*32+(l>>4)*8+j][col=nb*16+(l&15)]
// ---------------------------------------------------------------------------
__global__ __launch_bounds__(256) void knrm_wpack(
    const float* __restrict__ Wt, const float* __restrict__ We,
    const float* __restrict__ bt, const float* __restrict__ be,
    __bf16* __restrict__ Wtp, __bf16* __restrict__ Wep,
    float* __restrict__ bias)
{
    const int idx = blockIdx.x * 256 + threadIdx.x;   // 0..14335
    if (idx < AD) bias[idx] = bt[idx] + be[idx];
    const int tile = idx >> 6, l = idx & 63;
    bf16x8 h;
    if (tile < 160) {                                  // Wt pack, K pad 320
        const int s = tile >> 4, nb = tile & 15;
        const int col = nb * 16 + (l & 15);
        const int k0  = s * 32 + (l >> 4) * 8;
        #pragma unroll
        for (int j = 0; j < 8; ++j) {
            const int k = k0 + j;
            h[j] = (__bf16)((k < WORD) ? Wt[(size_t)k * AD + col] : 0.f);
        }
        *(bf16x8*)((char*)Wtp + (size_t)idx * 16) = h;
    } else {                                           // We pack, K=128 exact
        const int t2 = tile - 160;
        const int s = t2 >> 4, nb = t2 & 15;
        const int col = nb * 16 + (l & 15);
        const int k0  = s * 32 + (l >> 4) * 8;
        #pragma unroll
        for (int j = 0; j < 8; ++j)
            h[j] = (__bf16)We[(size_t)(k0 + j) * AD + col];
        *(bf16x8*)((char*)Wep + (size_t)(idx - 10240) * 16) = h;
    }
}

// ---------------------------------------------------------------------------
// P-GEMM: P[v] = emb[v] @ Wt, bf16, row layout PERMUTED within each 512B row:
// pos(col) = (col&15)*16 + (col>>6)*4 + ((col>>4)&3)  (fragment-gather order).
// 64 rows/block, 256 threads (4 waves = 4 N-quarters), K=320 (300 padded).
// ---------------------------------------------------------------------------
__global__ __launch_bounds__(256, 4) void knrm_pgemm(
    const float* __restrict__ emb,
    const __bf16* __restrict__ Wtp,
    char* __restrict__ P)
{
    __shared__ __align__(16) char sm[40960];   // A [64][320] bf16 swizzled
    const int tid = threadIdx.x;
    const int v0  = blockIdx.x * 64;

    #pragma unroll
    for (int u = 0; u < 20; ++u) {
        const int idx  = u * 256 + tid;        // 0..5119
        const int r    = idx / 80;
        const int slot = idx - r * 80;
        const int k    = slot * 4;
        f32x4 v = (f32x4){0.f, 0.f, 0.f, 0.f};
        if (k < WORD && v0 + r < VOCAB)
            v = *(const f32x4*)(emb + (size_t)(v0 + r) * WORD + k);
        bf16x4 hv;
        #pragma unroll
        for (int c = 0; c < 4; ++c) hv[c] = (__bf16)v[c];
        *(bf16x4*)(sm + ((r * 640 + slot * 8) ^ ((r & 7) << 4))) = hv;
    }
    __syncthreads();

    const int w  = tid >> 6;
    const int l  = tid & 63;
    const int lr = l & 15;
    const int lg = l >> 4;

    f32x4 acc[4][4];
    #pragma unroll
    for (int mf = 0; mf < 4; ++mf)
        #pragma unroll
        for (int nf = 0; nf < 4; ++nf)
            acc[mf][nf] = (f32x4){0.f, 0.f, 0.f, 0.f};

    #pragma unroll
    for (int t = 0; t < 10; ++t) {
        bf16x8 a[4];
        #pragma unroll
        for (int mf = 0; mf < 4; ++mf) {
            const int row = mf * 16 + lr;
            a[mf] = *(const bf16x8*)(sm +
                ((row * 640 + (t * 32 + lg * 8) * 2) ^ ((row & 7) << 4)));
        }
        bf16x8 wv[4];
        #pragma unroll
        for (int nf = 0; nf < 4; ++nf) {
            const int tile = t * 16 + w * 4 + nf;
            wv[nf] = *(const bf16x8*)((const char*)Wtp + (size_t)tile * 1024 + l * 16);
        }
        #pragma unroll
        for (int mf = 0; mf < 4; ++mf)
            #pragma unroll
            for (int nf = 0; nf < 4; ++nf)
                acc[mf][nf] = __builtin_amdgcn_mfma_f32_16x16x32_bf16(
                    a[mf], wv[nf], acc[mf][nf], 0, 0, 0);
    }

    #pragma unroll
    for (int mf = 0; mf < 4; ++mf)
        #pragma unroll
        for (int reg = 0; reg < 4; ++reg) {
            const int v = v0 + mf * 16 + lg * 4 + reg;
            if (v < VOCAB) {
                bf16x4 h;
                #pragma unroll
                for (int nf = 0; nf < 4; ++nf) h[nf] = (__bf16)acc[mf][nf][reg];
                *(bf16x4*)(P + (size_t)v * 512 + lr * 32 + w * 8) = h;
            }
        }
}

// ---------------------------------------------------------------------------
// Kernel Q: fp32 transform of 8 query rows/block; writes qhat bf16,
// XOR-swizzled per 32-row batch slab: byte = (q*512 + col*2) ^ ((q&7)<<4).
// ---------------------------------------------------------------------------
__global__ __launch_bounds__(256) void knrm_qtrans(
    const int* __restrict__ qtok,
    const float* __restrict__ qent,
    const float* __restrict__ emb,
    const float* __restrict__ Wt, const float* __restrict__ bt,
    const float* __restrict__ We, const float* __restrict__ be,
    char* __restrict__ qhatb)
{
    __shared__ float Xs[8 * 432];
    const int tid  = threadIdx.x;
    const int row0 = blockIdx.x * 8;

    for (int r = 0; r < 8; ++r) {
        const int row = row0 + r;
        const int tok = qtok[row] + 1;
        const float* __restrict__ er = emb + (size_t)tok * WORD;
        const float* __restrict__ xr = qent + (size_t)row * ENT;
        for (int c = tid; c < KDIM; c += 256)
            Xs[r * 432 + c] = (c < WORD) ? er[c] : xr[c - WORD];
    }
    __syncthreads();

    const int rg   = tid >> 6;
    const int cg   = tid & 63;
    const int col0 = cg * 4;

    float acc[2][4];
    #pragma unroll
    for (int j = 0; j < 2; ++j)
        acc[j][0] = acc[j][1] = acc[j][2] = acc[j][3] = 0.f;

    for (int i = 0; i < KDIM; i += 4) {
        const float* __restrict__ Wbase =
            (i < WORD) ? (Wt + (size_t)i * AD) : (We + (size_t)(i - WORD) * AD);
        float4 xv[2];
        #pragma unroll
        for (int j = 0; j < 2; ++j)
            xv[j] = *(const float4*)(&Xs[(rg * 2 + j) * 432 + i]);
        #pragma unroll
        for (int s = 0; s < 4; ++s) {
            const float4 w = *(const float4*)(Wbase + (size_t)s * AD + col0);
            #pragma unroll
            for (int j = 0; j < 2; ++j) {
                const float x = reinterpret_cast<const float*>(&xv[j])[s];
                acc[j][0] = fmaf(x, w.x, acc[j][0]);
                acc[j][1] = fmaf(x, w.y, acc[j][1]);
                acc[j][2] = fmaf(x, w.z, acc[j][2]);
                acc[j][3] = fmaf(x, w.w, acc[j][3]);
            }
        }
    }

    const float4 bt4 = *(const float4*)(bt + col0);
    const float4 be4 = *(const float4*)(be + col0);
    const float bias[4] = {bt4.x + be4.x, bt4.y + be4.y,
                           bt4.z + be4.z, bt4.w + be4.w};
    float ssq[2];
    #pragma unroll
    for (int j = 0; j < 2; ++j) {
        float s = 0.f;
        #pragma unroll
        for (int c = 0; c < 4; ++c) {
            const float v = fmaxf(acc[j][c] + bias[c], 0.f);
            acc[j][c] = v;
            s = fmaf(v, v, s);
        }
        ssq[j] = s;
    }
    #pragma unroll
    for (int m = 32; m; m >>= 1) {
        #pragma unroll
        for (int j = 0; j < 2; ++j)
            ssq[j] += __shfl_xor(ssq[j], m, 64);
    }
    char* qb = qhatb + (size_t)(blockIdx.x >> 2) * (QLEN * AD * 2);
    #pragma unroll
    for (int j = 0; j < 2; ++j) {
        const int q   = (blockIdx.x & 3) * 8 + rg * 2 + j;
        const int row = row0 + rg * 2 + j;
        const float rn = (qtok[row] == -1) ? 0.f
                                           : 1.f / (sqrtf(ssq[j]) + 1e-9f);
        bf16x4 h;
        #pragma unroll
        for (int c = 0; c < 4; ++c) h[c] = (__bf16)(acc[j][c] * rn);
        const int byte = (q * 512 + col0 * 2) ^ ((q & 7) << 4);
        *(bf16x4*)(qb + byte) = h;
    }
}

// ---------------------------------------------------------------------------
// Fused v6: 128 docs/block, 512 threads (8 waves, 2M x 4N). Transform is
// K=128 (ent only): dent A-frags straight from global (no LDS, no barriers),
// We frags from L2, P[tok] added via one 8B gather per fragment. Then
// relu/norm -> T in LDS -> sims MFMA -> RBF -> reductions.
// ---------------------------------------------------------------------------
__global__ __launch_bounds__(512, 4) void knrm_fused(
    const int* __restrict__ dtok,
    const float* __restrict__ dent,
    const char* __restrict__ Pp,
    const __bf16* __restrict__ Wep,
    const float* __restrict__ bias,
    const char* __restrict__ qhatb,
    float* __restrict__ ksum,    // [B, NK, QLEN]
    float* __restrict__ simsum)  // [B, QLEN]
{
    __shared__ __align__(16) char sm[65536 + 2560];
    float* red  = (float*)(sm + 65536);          // [12][32]
    float* ssq  = (float*)(sm + 65536 + 1536);   // [128]
    int*   toks = (int*)(sm + 65536 + 2048);     // [128] tok+1

    const int tid = threadIdx.x;
    const int b   = blockIdx.y;
    const int d0  = blockIdx.x * BM;
    const int drow0 = b * DLEN + d0;
    const int w  = tid >> 6;
    const int l  = tid & 63;
    const int lr = l & 15;
    const int lg = l >> 4;
    const int wM = w >> 2;       // 0..1 : doc half
    const int wN = w & 3;        // 0..3 : col quarter

    ((float*)(sm + 65536))[tid] = 0.f;           // zero red+ssq (512 floats)
    if (tid < BM) toks[tid] = dtok[drow0 + tid] + 1;
    __syncthreads();

    const float* __restrict__ dbase = dent + (size_t)drow0 * ENT;

    f32x4 acc[4][4];
    #pragma unroll
    for (int mf = 0; mf < 4; ++mf)
        #pragma unroll
        for (int nf = 0; nf < 4; ++nf)
            acc[mf][nf] = (f32x4){0.f, 0.f, 0.f, 0.f};

    // ---- transform: K=128, 4 steps, no LDS/barriers ----
    #pragma unroll
    for (int t = 0; t < 4; ++t) {
        bf16x8 a[4];
        #pragma unroll
        for (int mf = 0; mf < 4; ++mf) {
            const int row = wM * 64 + mf * 16 + lr;
            const float* rp = dbase + (size_t)row * ENT + t * 32 + lg * 8;
            const f32x4 u0 = *(const f32x4*)rp;
            const f32x4 u1 = *(const f32x4*)(rp + 4);
            #pragma unroll
            for (int c = 0; c < 4; ++c) {
                a[mf][c]     = (__bf16)u0[c];
                a[mf][c + 4] = (__bf16)u1[c];
            }
        }
        bf16x8 wv[4];
        #pragma unroll
        for (int nf = 0; nf < 4; ++nf) {
            const int tile = t * 16 + wN * 4 + nf;
            wv[nf] = *(const bf16x8*)((const char*)Wep + (size_t)tile * 1024 + l * 16);
        }
        #pragma unroll
        for (int mf = 0; mf < 4; ++mf)
            #pragma unroll
            for (int nf = 0; nf < 4; ++nf)
                acc[mf][nf] = __builtin_amdgcn_mfma_f32_16x16x32_bf16(
                    a[mf], wv[nf], acc[mf][nf], 0, 0, 0);
    }

    // ---- P gather: one bf16x4 (nf=0..3) per (mf,reg) fragment ----
    bf16x4 pv[4][4];
    #pragma unroll
    for (int mf = 0; mf < 4; ++mf)
        #pragma unroll
        for (int reg = 0; reg < 4; ++reg) {
            const int doc = wM * 64 + mf * 16 + lg * 4 + reg;
            pv[mf][reg] = *(const bf16x4*)(Pp +
                (size_t)toks[doc] * 512 + lr * 32 + wN * 8);
        }

    // ---- bias + P + relu + row square-sums ----
    float bv[4];
    #pragma unroll
    for (int nf = 0; nf < 4; ++nf) bv[nf] = bias[wN * 64 + nf * 16 + lr];
    float sq[4][4];
    #pragma unroll
    for (int mf = 0; mf < 4; ++mf)
        #pragma unroll
        for (int reg = 0; reg < 4; ++reg) {
            float s = 0.f;
            #pragma unroll
            for (int nf = 0; nf < 4; ++nf) {
                const float v = fmaxf(acc[mf][nf][reg] + (float)pv[mf][reg][nf]
                                      + bv[nf], 0.f);
                acc[mf][nf][reg] = v;
                s = fmaf(v, v, s);
            }
            sq[mf][reg] = s;
        }
    #pragma unroll
    for (int m = 1; m <= 8; m <<= 1)
        #pragma unroll
        for (int mf = 0; mf < 4; ++mf)
            #pragma unroll
            for (int reg = 0; reg < 4; ++reg)
                sq[mf][reg] += __shfl_xor(sq[mf][reg], m, 64);
    if (lr == 0) {
        #pragma unroll
        for (int mf = 0; mf < 4; ++mf)
            #pragma unroll
            for (int reg = 0; reg < 4; ++reg)
                atomicAdd(&ssq[wM * 64 + mf * 16 + lg * 4 + reg], sq[mf][reg]);
    }
    // write T [doc][256] bf16: byte = (doc*512+col*2)^((doc&7)<<4)
    #pragma unroll
    for (int mf = 0; mf < 4; ++mf)
        #pragma unroll
        for (int nf = 0; nf < 4; ++nf)
            #pragma unroll
            for (int reg = 0; reg < 4; ++reg) {
                const int doc  = wM * 64 + mf * 16 + lg * 4 + reg;
                const int col  = wN * 64 + nf * 16 + lr;
                const int byte = (doc * 512 + col * 2) ^ ((doc & 7) << 4);
                *(__bf16*)(sm + byte) = (__bf16)acc[mf][nf][reg];
            }
    __syncthreads();

    // ---- sims: wave w owns docs w*16..w*16+15 (M), 32 q (2 N-frags) ----
    const int tdoc = w * 16 + lr;
    const char* __restrict__ qb = qhatb + (size_t)b * (QLEN * AD * 2);
    f32x4 s0 = (f32x4){0.f, 0.f, 0.f, 0.f};
    f32x4 s1 = (f32x4){0.f, 0.f, 0.f, 0.f};
    #pragma unroll
    for (int s = 0; s < 8; ++s) {
        const bf16x8 ta = *(const bf16x8*)(sm +
            ((tdoc * 512 + s * 64 + lg * 16) ^ ((tdoc & 7) << 4)));
        const bf16x8 q0 = *(const bf16x8*)(qb +
            ((lr * 512 + s * 64 + lg * 16) ^ ((lr & 7) << 4)));
        const bf16x8 q1 = *(const bf16x8*)(qb +
            (((lr + 16) * 512 + s * 64 + lg * 16) ^ (((lr + 16) & 7) << 4)));
        s0 = __builtin_amdgcn_mfma_f32_16x16x32_bf16(ta, q0, s0, 0, 0, 0);
        s1 = __builtin_amdgcn_mfma_f32_16x16x32_bf16(ta, q1, s1, 0, 0, 0);
    }

    // ---- RBF: lane holds 4 docs (regs) x q = lr (s0) and lr+16 (s1) ----
    float kq0[12], kq1[12];
    #pragma unroll
    for (int k = 0; k < 12; ++k) { kq0[k] = 0.f; kq1[k] = 0.f; }
    #pragma unroll
    for (int reg = 0; reg < 4; ++reg) {
        const int doc = w * 16 + lg * 4 + reg;
        const float dnv = (toks[doc] == 0) ? 0.f
                                           : 1.f / (sqrtf(ssq[doc]) + 1e-9f);
        const float sv0 = s0[reg] * dnv;
        const float sv1 = s1[reg] * dnv;
        kq0[11] += sv0;
        kq1[11] += sv1;
        #pragma unroll
        for (int k = 0; k < NK; ++k) {
            const float t0 = sv0 - d_mus[k];
            const float t1 = sv1 - d_mus[k];
            kq0[k] += __expf(d_coef[k] * t0 * t0);
            kq1[k] += __expf(d_coef[k] * t1 * t1);
        }
    }
    #pragma unroll
    for (int m = 16; m <= 32; m <<= 1)
        #pragma unroll
        for (int k = 0; k < 12; ++k) {
            kq0[k] += __shfl_xor(kq0[k], m, 64);
            kq1[k] += __shfl_xor(kq1[k], m, 64);
        }
    if (lg == 0) {
        #pragma unroll
        for (int k = 0; k < 12; ++k) {
            atomicAdd(&red[k * 32 + lr], kq0[k]);
            atomicAdd(&red[k * 32 + 16 + lr], kq1[k]);
        }
    }
    __syncthreads();

    for (int i = tid; i < 384; i += 512) {
        const int k = i >> 5, qq = i & 31;
        if (k < NK) atomicAdd(&ksum[((size_t)b * NK + k) * QLEN + qq], red[i]);
        else        atomicAdd(&simsum[b * QLEN + qq], red[i]);
    }
}

// ---------------------------------------------------------------------------
__global__ __launch_bounds__(384) void knrm_final(
    const float* __restrict__ ksum,
    const float* __restrict__ simsum,
    const float* __restrict__ Wc, const float* __restrict__ bc,
    float* __restrict__ out)
{
    __shared__ float redq[NK][QLEN];
    __shared__ float res[NK];
    const int b = blockIdx.x;
    const int t = threadIdx.x;
    if (t < NK * QLEN) {
        const int k = t >> 5;
        const int q = t & 31;
        const float ms = simsum[b * QLEN + q];
        redq[k][q] = (ms != 0.0f)
            ? logf(ksum[((size_t)b * NK + k) * QLEN + q] + 1e-6f)
            : 0.0f;
    }
    __syncthreads();
    if (t < NK) {
        float s = 0.f;
        for (int q = 0; q < QLEN; ++q) s += redq[t][q];
        res[t] = s;
    }
    __syncthreads();
    if (t == 0) {
        float s = bc[0];
        for (int k = 0; k < NK; ++k) s += res[k] * Wc[k];
        out[b] = s;
    }
}

// ---------------------------------------------------------------------------
extern "C" void kernel_launch(void* const* d_in, const int* in_sizes, int n_in,
                              void* d_out, int out_size, void* d_ws, size_t ws_size,
                              hipStream_t stream)
{
    (void)in_sizes; (void)n_in; (void)out_size; (void)ws_size;
    const int*   qtok = (const int*)d_in[0];
    const int*   dtok = (const int*)d_in[1];
    const float* qent = (const float*)d_in[2];
    const float* dent = (const float*)d_in[3];
    const float* emb  = (const float*)d_in[4];
    const float* Wt   = (const float*)d_in[5];
    const float* bt   = (const float*)d_in[6];
    const float* We   = (const float*)d_in[7];
    const float* be   = (const float*)d_in[8];
    const float* Wc   = (const float*)d_in[9];
    const float* bc   = (const float*)d_in[10];
    float* out = (float*)d_out;

    char* ws = (char*)d_ws;
    char*   qhatb = ws;                                  // 1 MB
    __bf16* Wtp   = (__bf16*)(ws + 1048576);             // 160 KB
    __bf16* Wep   = (__bf16*)(ws + 1212416);             // 64 KB
    float*  bias  = (float*)(ws + 1277952);              // 1 KB
    float*  ksum  = (float*)(ws + 1278976);              // 90112 B
    float*  simsum= (float*)(ws + 1369088);              // 8192 B
    char*   P     = ws + 1377280;                        // 25.6 MB bf16 permuted

    hipMemsetAsync(ksum, 0, (size_t)(90112 + 8192), stream);

    knrm_wpack<<<dim3(56), dim3(256), 0, stream>>>(Wt, We, bt, be, Wtp, Wep, bias);
    knrm_pgemm<<<dim3((VOCAB + 63) / 64), dim3(256), 0, stream>>>(emb, Wtp, P);
    knrm_qtrans<<<dim3((B_ * QLEN) / 8), dim3(256), 0, stream>>>(
        qtok, qent, emb, Wt, bt, We, be, qhatb);
    knrm_fused<<<dim3(DLEN / BM, B_), dim3(512), 0, stream>>>(
        dtok, dent, P, Wep, bias, qhatb, ksum, simsum);
    knrm_final<<<dim3(B_), dim3(384), 0, stream>>>(ksum, simsum, Wc, bc, out);
}

// Round 7
// 134.286 us; speedup vs baseline: 1.1028x; 1.1028x over previous
//
#include <hip/hip_runtime.h>
#include <math.h>

#define B_    64
#define QLEN  32
#define DLEN  2048
#define WORD  300
#define ENT   128
#define AD    256
#define NK    11
#define VOCAB 50000

typedef __bf16 bf16x8 __attribute__((ext_vector_type(8)));
typedef __bf16 bf16x4 __attribute__((ext_vector_type(4)));
typedef float  f32x4  __attribute__((ext_vector_type(4)));

static __device__ const float d_mus[NK] =
    {-0.9f,-0.7f,-0.5f,-0.3f,-0.1f,0.1f,0.3f,0.5f,0.7f,0.9f,1.0f};
static __device__ const float d_coef[NK] =
    {-50.f,-50.f,-50.f,-50.f,-50.f,-50.f,-50.f,-50.f,-50.f,-50.f,-500000.f};

// ---------------------------------------------------------------------------
// W-pack: Wtp (K=320 pad) and Wep (K=128) in MFMA-B fragment order.
// tile = 64 lanes x 16B; lane l elem j: B[k=s*32+(l>>4)*8+j][col=nb*16+(l&15)]
// ---------------------------------------------------------------------------
__global__ __launch_bounds__(256) void knrm_wpack(
    const float* __restrict__ Wt, const float* __restrict__ We,
    const float* __restrict__ bt, const float* __restrict__ be,
    __bf16* __restrict__ Wtp, __bf16* __restrict__ Wep,
    float* __restrict__ bias)
{
    const int idx = blockIdx.x * 256 + threadIdx.x;   // 0..14335
    if (idx < AD) bias[idx] = bt[idx] + be[idx];
    const int tile = idx >> 6, l = idx & 63;
    bf16x8 h;
    if (tile < 160) {
        const int s = tile >> 4, nb = tile & 15;
        const int col = nb * 16 + (l & 15);
        const int k0  = s * 32 + (l >> 4) * 8;
        #pragma unroll
        for (int j = 0; j < 8; ++j) {
            const int k = k0 + j;
            h[j] = (__bf16)((k < WORD) ? Wt[(size_t)k * AD + col] : 0.f);
        }
        *(bf16x8*)((char*)Wtp + (size_t)idx * 16) = h;
    } else {
        const int t2 = tile - 160;
        const int s = t2 >> 4, nb = t2 & 15;
        const int col = nb * 16 + (l & 15);
        const int k0  = s * 32 + (l >> 4) * 8;
        #pragma unroll
        for (int j = 0; j < 8; ++j)
            h[j] = (__bf16)We[(size_t)(k0 + j) * AD + col];
        *(bf16x8*)((char*)Wep + (size_t)(idx - 10240) * 16) = h;
    }
}

// ---------------------------------------------------------------------------
// P-GEMM v2 (no LDS, no barriers): P[v] = emb[v] @ Wt, bf16, permuted rows:
// pos(col) = (col&15)*16 + (col>>6)*4 + ((col>>4)&3), 512 B/row.
// 64 rows/block, 256 thr (4 waves = N-quarters), A-frags direct from global.
// ---------------------------------------------------------------------------
__global__ __launch_bounds__(256) void knrm_pgemm(
    const float* __restrict__ emb,
    const __bf16* __restrict__ Wtp,
    char* __restrict__ P)
{
    const int tid = threadIdx.x;
    const int v0  = blockIdx.x * 64;
    const int w  = tid >> 6;
    const int l  = tid & 63;
    const int lr = l & 15;
    const int lg = l >> 4;

    f32x4 acc[4][4];
    #pragma unroll
    for (int mf = 0; mf < 4; ++mf)
        #pragma unroll
        for (int nf = 0; nf < 4; ++nf)
            acc[mf][nf] = (f32x4){0.f, 0.f, 0.f, 0.f};

    #pragma unroll
    for (int t = 0; t < 10; ++t) {
        const int k0 = t * 32 + lg * 8;
        bf16x8 a[4];
        #pragma unroll
        for (int mf = 0; mf < 4; ++mf) {
            int row = v0 + mf * 16 + lr;
            if (row >= VOCAB) row = VOCAB - 1;
            const float* rp = emb + (size_t)row * WORD + k0;
            const f32x4 z = (f32x4){0.f, 0.f, 0.f, 0.f};
            const f32x4 u0 = (k0 + 4 <= WORD) ? *(const f32x4*)rp : z;
            const f32x4 u1 = (k0 + 8 <= WORD) ? *(const f32x4*)(rp + 4) : z;
            #pragma unroll
            for (int c = 0; c < 4; ++c) {
                a[mf][c]     = (__bf16)u0[c];
                a[mf][c + 4] = (__bf16)u1[c];
            }
        }
        bf16x8 wv[4];
        #pragma unroll
        for (int nf = 0; nf < 4; ++nf) {
            const int tile = t * 16 + w * 4 + nf;
            wv[nf] = *(const bf16x8*)((const char*)Wtp + (size_t)tile * 1024 + l * 16);
        }
        #pragma unroll
        for (int mf = 0; mf < 4; ++mf)
            #pragma unroll
            for (int nf = 0; nf < 4; ++nf)
                acc[mf][nf] = __builtin_amdgcn_mfma_f32_16x16x32_bf16(
                    a[mf], wv[nf], acc[mf][nf], 0, 0, 0);
    }

    #pragma unroll
    for (int mf = 0; mf < 4; ++mf)
        #pragma unroll
        for (int reg = 0; reg < 4; ++reg) {
            const int v = v0 + mf * 16 + lg * 4 + reg;
            if (v < VOCAB) {
                bf16x4 h;
                #pragma unroll
                for (int nf = 0; nf < 4; ++nf) h[nf] = (__bf16)acc[mf][nf][reg];
                *(bf16x4*)(P + (size_t)v * 512 + lr * 32 + w * 8) = h;
            }
        }
}

// ---------------------------------------------------------------------------
// trans<MODE>: 32 rows/block, 256 thr (4 waves = N-quarters, mf-loop of 2).
// relu(P[tok] + ent@We + bias). MODE 0 (doc): write That row-major bf16 +
// dnv (0 for pad). MODE 1 (query): write qhat row-major bf16, normalized,
// padded rows zeroed.
// ---------------------------------------------------------------------------
template<int MODE>
__global__ __launch_bounds__(256) void knrm_trans(
    const int* __restrict__ tok,
    const float* __restrict__ ent,
    const char* __restrict__ Pp,
    const __bf16* __restrict__ Wep,
    const float* __restrict__ bias,
    int row_base,
    char* __restrict__ Tout,
    float* __restrict__ dnv)
{
    __shared__ __align__(16) char sm[16384 + 256];   // T [32][256] bf16 swz
    float* ssq  = (float*)(sm + 16384);              // [32]
    int*   toks = (int*)(sm + 16384 + 128);          // [32]

    const int tid  = threadIdx.x;
    const int row0 = row_base + blockIdx.y * DLEN + blockIdx.x * 32;
    if (tid < 32) { toks[tid] = tok[row0 + tid] + 1; ssq[tid] = 0.f; }
    __syncthreads();

    const int wN = tid >> 6;
    const int l  = tid & 63;
    const int lr = l & 15;
    const int lg = l >> 4;
    const float* __restrict__ ebase = ent + (size_t)row0 * ENT;

    f32x4 acc[2][4];
    #pragma unroll
    for (int mf = 0; mf < 2; ++mf)
        #pragma unroll
        for (int nf = 0; nf < 4; ++nf)
            acc[mf][nf] = (f32x4){0.f, 0.f, 0.f, 0.f};

    #pragma unroll
    for (int t = 0; t < 4; ++t) {
        bf16x8 a[2];
        #pragma unroll
        for (int mf = 0; mf < 2; ++mf) {
            const float* rp = ebase + (size_t)(mf * 16 + lr) * ENT + t * 32 + lg * 8;
            const f32x4 u0 = *(const f32x4*)rp;
            const f32x4 u1 = *(const f32x4*)(rp + 4);
            #pragma unroll
            for (int c = 0; c < 4; ++c) {
                a[mf][c]     = (__bf16)u0[c];
                a[mf][c + 4] = (__bf16)u1[c];
            }
        }
        bf16x8 wv[4];
        #pragma unroll
        for (int nf = 0; nf < 4; ++nf) {
            const int tile = t * 16 + wN * 4 + nf;
            wv[nf] = *(const bf16x8*)((const char*)Wep + (size_t)tile * 1024 + l * 16);
        }
        #pragma unroll
        for (int mf = 0; mf < 2; ++mf)
            #pragma unroll
            for (int nf = 0; nf < 4; ++nf)
                acc[mf][nf] = __builtin_amdgcn_mfma_f32_16x16x32_bf16(
                    a[mf], wv[nf], acc[mf][nf], 0, 0, 0);
    }

    // P gather: bf16x4 per (mf,reg)
    bf16x4 pv[2][4];
    #pragma unroll
    for (int mf = 0; mf < 2; ++mf)
        #pragma unroll
        for (int reg = 0; reg < 4; ++reg) {
            const int doc = mf * 16 + lg * 4 + reg;
            pv[mf][reg] = *(const bf16x4*)(Pp +
                (size_t)toks[doc] * 512 + lr * 32 + wN * 8);
        }

    float bv[4];
    #pragma unroll
    for (int nf = 0; nf < 4; ++nf) bv[nf] = bias[wN * 64 + nf * 16 + lr];
    float sq[2][4];
    #pragma unroll
    for (int mf = 0; mf < 2; ++mf)
        #pragma unroll
        for (int reg = 0; reg < 4; ++reg) {
            float s = 0.f;
            #pragma unroll
            for (int nf = 0; nf < 4; ++nf) {
                const float v = fmaxf(acc[mf][nf][reg] + (float)pv[mf][reg][nf]
                                      + bv[nf], 0.f);
                acc[mf][nf][reg] = v;
                s = fmaf(v, v, s);
            }
            sq[mf][reg] = s;
        }
    #pragma unroll
    for (int m = 1; m <= 8; m <<= 1)
        #pragma unroll
        for (int mf = 0; mf < 2; ++mf)
            #pragma unroll
            for (int reg = 0; reg < 4; ++reg)
                sq[mf][reg] += __shfl_xor(sq[mf][reg], m, 64);
    if (lr == 0) {
        #pragma unroll
        for (int mf = 0; mf < 2; ++mf)
            #pragma unroll
            for (int reg = 0; reg < 4; ++reg)
                atomicAdd(&ssq[mf * 16 + lg * 4 + reg], sq[mf][reg]);
    }
    // T -> LDS swizzled: byte = (doc*512 + col*2) ^ ((doc&7)<<4)
    #pragma unroll
    for (int mf = 0; mf < 2; ++mf)
        #pragma unroll
        for (int nf = 0; nf < 4; ++nf)
            #pragma unroll
            for (int reg = 0; reg < 4; ++reg) {
                const int doc  = mf * 16 + lg * 4 + reg;
                const int col  = wN * 64 + nf * 16 + lr;
                const int byte = (doc * 512 + col * 2) ^ ((doc & 7) << 4);
                *(__bf16*)(sm + byte) = (__bf16)acc[mf][nf][reg];
            }
    __syncthreads();

    // readout: 32 rows x 32 chunks of 16B
    #pragma unroll
    for (int it = 0; it < 4; ++it) {
        const int idx = it * 256 + tid;
        const int row = idx >> 5, c = idx & 31;
        const int byte = (row * 512 + c * 16) ^ ((row & 7) << 4);
        bf16x8 hv = *(const bf16x8*)(sm + byte);
        if (MODE == 0) {
            *(bf16x8*)(Tout + ((size_t)blockIdx.y * DLEN + blockIdx.x * 32 + row)
                              * 512 + c * 16) = hv;
        } else {
            const float rn = (toks[row] == 0) ? 0.f
                                              : 1.f / (sqrtf(ssq[row]) + 1e-9f);
            #pragma unroll
            for (int j = 0; j < 8; ++j) hv[j] = (__bf16)((float)hv[j] * rn);
            *(bf16x8*)(Tout + (size_t)(blockIdx.x * 32 + row) * 512 + c * 16) = hv;
        }
    }
    if (MODE == 0 && tid < 32)
        dnv[row0 + tid] = (toks[tid] == 0) ? 0.f
                                           : 1.f / (sqrtf(ssq[tid]) + 1e-9f);
}

// ---------------------------------------------------------------------------
// sims: 128 docs x 32 q per block, 256 thr (4 waves x 32 docs). That/qhat
// read straight from global (row-major bf16). RBF + reductions.
// ---------------------------------------------------------------------------
__global__ __launch_bounds__(256) void knrm_sims(
    const char* __restrict__ That,
    const char* __restrict__ qhat,
    const float* __restrict__ dnv,
    int g0,
    float* __restrict__ ksum,
    float* __restrict__ simsum)
{
    __shared__ float red[384];
    const int tid = threadIdx.x;
    const int bl  = blockIdx.y;          // chunk-local batch
    const int bg  = g0 + bl;             // global batch
    const int d0  = blockIdx.x * 128;
    const int w  = tid >> 6;
    const int l  = tid & 63;
    const int lr = l & 15;
    const int lg = l >> 4;
    for (int i = tid; i < 384; i += 256) red[i] = 0.f;
    __syncthreads();

    const char* __restrict__ Tb = That + ((size_t)bl * DLEN + d0 + w * 32) * 512;
    const char* __restrict__ qb = qhat + (size_t)bg * QLEN * 512;

    f32x4 acc[2][2];
    #pragma unroll
    for (int dt = 0; dt < 2; ++dt)
        #pragma unroll
        for (int qt = 0; qt < 2; ++qt)
            acc[dt][qt] = (f32x4){0.f, 0.f, 0.f, 0.f};

    #pragma unroll
    for (int s = 0; s < 8; ++s) {
        bf16x8 a[2], qv[2];
        #pragma unroll
        for (int dt = 0; dt < 2; ++dt)
            a[dt] = *(const bf16x8*)(Tb + (size_t)(dt * 16 + lr) * 512
                                     + s * 64 + lg * 16);
        #pragma unroll
        for (int qt = 0; qt < 2; ++qt)
            qv[qt] = *(const bf16x8*)(qb + (size_t)(qt * 16 + lr) * 512
                                      + s * 64 + lg * 16);
        #pragma unroll
        for (int dt = 0; dt < 2; ++dt)
            #pragma unroll
            for (int qt = 0; qt < 2; ++qt)
                acc[dt][qt] = __builtin_amdgcn_mfma_f32_16x16x32_bf16(
                    a[dt], qv[qt], acc[dt][qt], 0, 0, 0);
    }

    float dn[2][4];
    #pragma unroll
    for (int dt = 0; dt < 2; ++dt) {
        const f32x4 dv = *(const f32x4*)(dnv + (size_t)bg * DLEN + d0
                                         + w * 32 + dt * 16 + lg * 4);
        #pragma unroll
        for (int r = 0; r < 4; ++r) dn[dt][r] = dv[r];
    }

    #pragma unroll
    for (int qt = 0; qt < 2; ++qt) {
        float kq[12];
        #pragma unroll
        for (int k = 0; k < 12; ++k) kq[k] = 0.f;
        #pragma unroll
        for (int dt = 0; dt < 2; ++dt)
            #pragma unroll
            for (int reg = 0; reg < 4; ++reg) {
                const float sv = acc[dt][qt][reg] * dn[dt][reg];
                kq[11] += sv;
                #pragma unroll
                for (int k = 0; k < NK; ++k) {
                    const float t = sv - d_mus[k];
                    kq[k] += __expf(d_coef[k] * t * t);
                }
            }
        #pragma unroll
        for (int m = 16; m <= 32; m <<= 1)
            #pragma unroll
            for (int k = 0; k < 12; ++k)
                kq[k] += __shfl_xor(kq[k], m, 64);
        if (lg == 0) {
            #pragma unroll
            for (int k = 0; k < 12; ++k)
                atomicAdd(&red[k * 32 + qt * 16 + lr], kq[k]);
        }
    }
    __syncthreads();

    for (int i = tid; i < 384; i += 256) {
        const int k = i >> 5, q = i & 31;
        if (k < NK) atomicAdd(&ksum[((size_t)bg * NK + k) * QLEN + q], red[i]);
        else        atomicAdd(&simsum[bg * QLEN + q], red[i]);
    }
}

// ---------------------------------------------------------------------------
__global__ __launch_bounds__(384) void knrm_final(
    const float* __restrict__ ksum,
    const float* __restrict__ simsum,
    const float* __restrict__ Wc, const float* __restrict__ bc,
    float* __restrict__ out)
{
    __shared__ float redq[NK][QLEN];
    __shared__ float res[NK];
    const int b = blockIdx.x;
    const int t = threadIdx.x;
    if (t < NK * QLEN) {
        const int k = t >> 5;
        const int q = t & 31;
        const float ms = simsum[b * QLEN + q];
        redq[k][q] = (ms != 0.0f)
            ? logf(ksum[((size_t)b * NK + k) * QLEN + q] + 1e-6f)
            : 0.0f;
    }
    __syncthreads();
    if (t < NK) {
        float s = 0.f;
        for (int q = 0; q < QLEN; ++q) s += redq[t][q];
        res[t] = s;
    }
    __syncthreads();
    if (t == 0) {
        float s = bc[0];
        for (int k = 0; k < NK; ++k) s += res[k] * Wc[k];
        out[b] = s;
    }
}

// ---------------------------------------------------------------------------
extern "C" void kernel_launch(void* const* d_in, const int* in_sizes, int n_in,
                              void* d_out, int out_size, void* d_ws, size_t ws_size,
                              hipStream_t stream)
{
    (void)in_sizes; (void)n_in; (void)out_size;
    const int*   qtok = (const int*)d_in[0];
    const int*   dtok = (const int*)d_in[1];
    const float* qent = (const float*)d_in[2];
    const float* dent = (const float*)d_in[3];
    const float* emb  = (const float*)d_in[4];
    const float* Wt   = (const float*)d_in[5];
    const float* bt   = (const float*)d_in[6];
    const float* We   = (const float*)d_in[7];
    const float* be   = (const float*)d_in[8];
    const float* Wc   = (const float*)d_in[9];
    const float* bc   = (const float*)d_in[10];
    float* out = (float*)d_out;

    char* ws = (char*)d_ws;
    const size_t off_qhat = 0;                               // 1,048,576
    const size_t off_Wtp  = off_qhat + 1048576;              //   163,840
    const size_t off_Wep  = off_Wtp  + 163840;               //    65,536
    const size_t off_bias = off_Wep  + 65536;                //     1,024
    const size_t off_ksum = off_bias + 1024;                 //    90,112
    const size_t off_sim  = off_ksum + 90112;                //     8,192
    const size_t off_dnv  = off_sim  + 8192;                 //   524,288
    const size_t off_P    = off_dnv  + 524288;               // 25,600,000
    const size_t off_That = off_P    + 25600000;

    char*   qhat  = ws + off_qhat;
    __bf16* Wtp   = (__bf16*)(ws + off_Wtp);
    __bf16* Wep   = (__bf16*)(ws + off_Wep);
    float*  bias  = (float*)(ws + off_bias);
    float*  ksum  = (float*)(ws + off_ksum);
    float*  simsum= (float*)(ws + off_sim);
    float*  dnv   = (float*)(ws + off_dnv);
    char*   P     = ws + off_P;
    char*   That  = ws + off_That;

    const size_t slab = (size_t)DLEN * 512;   // 1 MB per batch of That
    int G = 1;
    if      (ws_size >= off_That + 64 * slab) G = 64;
    else if (ws_size >= off_That +  8 * slab) G = 8;
    else if (ws_size >= off_That +  2 * slab) G = 2;

    hipMemsetAsync(ksum, 0, (size_t)(90112 + 8192), stream);

    knrm_wpack<<<dim3(56), dim3(256), 0, stream>>>(Wt, We, bt, be, Wtp, Wep, bias);
    knrm_pgemm<<<dim3((VOCAB + 63) / 64), dim3(256), 0, stream>>>(emb, Wtp, P);
    knrm_trans<1><<<dim3(64, 1), dim3(256), 0, stream>>>(
        qtok, qent, P, Wep, bias, 0, qhat, nullptr);

    for (int g0 = 0; g0 < B_; g0 += G) {
        knrm_trans<0><<<dim3(64, G), dim3(256), 0, stream>>>(
            dtok, dent, P, Wep, bias, g0 * DLEN, That, dnv);
        knrm_sims<<<dim3(16, G), dim3(256), 0, stream>>>(
            That, qhat, dnv, g0, ksum, simsum);
    }

    knrm_final<<<dim3(B_), dim3(384), 0, stream>>>(ksum, simsum, Wc, bc, out);
}

// Round 8
// 106.736 us; speedup vs baseline: 1.3875x; 1.2581x over previous
//
#include <hip/hip_runtime.h>
#include <math.h>

#define B_    64
#define QLEN  32
#define DLEN  2048
#define WORD  300
#define ENT   128
#define AD    256
#define NK    11
#define VOCAB 50000

typedef __bf16 bf16x8 __attribute__((ext_vector_type(8)));
typedef __bf16 bf16x4 __attribute__((ext_vector_type(4)));
typedef float  f32x4  __attribute__((ext_vector_type(4)));

static __device__ const float d_mus[NK] =
    {-0.9f,-0.7f,-0.5f,-0.3f,-0.1f,0.1f,0.3f,0.5f,0.7f,0.9f,1.0f};
static __device__ const float d_coef[NK] =
    {-50.f,-50.f,-50.f,-50.f,-50.f,-50.f,-50.f,-50.f,-50.f,-50.f,-500000.f};

// ---------------------------------------------------------------------------
// W-pack: Wtp (K=320 pad, 160 tiles) + Wep (K=128, 64 tiles), MFMA-B order.
// tile = 64 lanes x 16B; lane l elem j: B[k=s*32+(l>>4)*8+j][col=nb*16+(l&15)]
// ---------------------------------------------------------------------------
__global__ __launch_bounds__(256) void knrm_wpack(
    const float* __restrict__ Wt, const float* __restrict__ We,
    const float* __restrict__ bt, const float* __restrict__ be,
    __bf16* __restrict__ Wtp, __bf16* __restrict__ Wep,
    float* __restrict__ bias)
{
    const int idx = blockIdx.x * 256 + threadIdx.x;   // 0..14335
    if (idx < AD) bias[idx] = bt[idx] + be[idx];
    const int tile = idx >> 6, l = idx & 63;
    bf16x8 h;
    if (tile < 160) {
        const int s = tile >> 4, nb = tile & 15;
        const int col = nb * 16 + (l & 15);
        const int k0  = s * 32 + (l >> 4) * 8;
        #pragma unroll
        for (int j = 0; j < 8; ++j) {
            const int k = k0 + j;
            h[j] = (__bf16)((k < WORD) ? Wt[(size_t)k * AD + col] : 0.f);
        }
        *(bf16x8*)((char*)Wtp + (size_t)idx * 16) = h;
    } else {
        const int t2 = tile - 160;
        const int s = t2 >> 4, nb = t2 & 15;
        const int col = nb * 16 + (l & 15);
        const int k0  = s * 32 + (l >> 4) * 8;
        #pragma unroll
        for (int j = 0; j < 8; ++j)
            h[j] = (__bf16)We[(size_t)(k0 + j) * AD + col];
        *(bf16x8*)((char*)Wep + (size_t)(idx - 10240) * 16) = h;
    }
}

// ---------------------------------------------------------------------------
// P-GEMM (LDS-staged A, cvt once): P[v] = emb[v] @ Wt, bf16, permuted rows:
// pos(col) = (col&15)*16 + (col>>6)*4 + ((col>>4)&3), 512 B/row.
// ---------------------------------------------------------------------------
__global__ __launch_bounds__(256) void knrm_pgemm(
    const float* __restrict__ emb,
    const __bf16* __restrict__ Wtp,
    char* __restrict__ P)
{
    __shared__ __align__(16) char sm[40960];   // A [64][320] bf16 swizzled
    const int tid = threadIdx.x;
    const int v0  = blockIdx.x * 64;

    #pragma unroll
    for (int u = 0; u < 20; ++u) {
        const int idx  = u * 256 + tid;        // 0..5119
        const int r    = idx / 80;
        const int slot = idx - r * 80;
        const int k    = slot * 4;
        f32x4 v = (f32x4){0.f, 0.f, 0.f, 0.f};
        if (k < WORD && v0 + r < VOCAB)
            v = *(const f32x4*)(emb + (size_t)(v0 + r) * WORD + k);
        bf16x4 hv;
        #pragma unroll
        for (int c = 0; c < 4; ++c) hv[c] = (__bf16)v[c];
        *(bf16x4*)(sm + ((r * 640 + slot * 8) ^ ((r & 7) << 4))) = hv;
    }
    __syncthreads();

    const int w  = tid >> 6;
    const int l  = tid & 63;
    const int lr = l & 15;
    const int lg = l >> 4;

    f32x4 acc[4][4];
    #pragma unroll
    for (int mf = 0; mf < 4; ++mf)
        #pragma unroll
        for (int nf = 0; nf < 4; ++nf)
            acc[mf][nf] = (f32x4){0.f, 0.f, 0.f, 0.f};

    #pragma unroll
    for (int t = 0; t < 10; ++t) {
        bf16x8 a[4];
        #pragma unroll
        for (int mf = 0; mf < 4; ++mf) {
            const int row = mf * 16 + lr;
            a[mf] = *(const bf16x8*)(sm +
                ((row * 640 + t * 64 + lg * 16) ^ ((row & 7) << 4)));
        }
        bf16x8 wv[4];
        #pragma unroll
        for (int nf = 0; nf < 4; ++nf) {
            const int tile = t * 16 + w * 4 + nf;
            wv[nf] = *(const bf16x8*)((const char*)Wtp + (size_t)tile * 1024 + l * 16);
        }
        #pragma unroll
        for (int mf = 0; mf < 4; ++mf)
            #pragma unroll
            for (int nf = 0; nf < 4; ++nf)
                acc[mf][nf] = __builtin_amdgcn_mfma_f32_16x16x32_bf16(
                    a[mf], wv[nf], acc[mf][nf], 0, 0, 0);
    }

    #pragma unroll
    for (int mf = 0; mf < 4; ++mf)
        #pragma unroll
        for (int reg = 0; reg < 4; ++reg) {
            const int v = v0 + mf * 16 + lg * 4 + reg;
            if (v < VOCAB) {
                bf16x4 h;
                #pragma unroll
                for (int nf = 0; nf < 4; ++nf) h[nf] = (__bf16)acc[mf][nf][reg];
                *(bf16x4*)(P + (size_t)v * 512 + lr * 32 + w * 8) = h;
            }
        }
}

// ---------------------------------------------------------------------------
// Query transform: 32 rows/block, grid 64. relu(P[tok]+qent@We+bias),
// normalize, zero padded rows; write qhat row-major bf16 [2048][256].
// ---------------------------------------------------------------------------
__global__ __launch_bounds__(256) void knrm_qtrans(
    const int* __restrict__ tok,
    const float* __restrict__ ent,
    const char* __restrict__ Pp,
    const __bf16* __restrict__ Wep,
    const float* __restrict__ bias,
    char* __restrict__ qhat)
{
    __shared__ __align__(16) char sm[16384 + 256];   // T [32][256] bf16 swz
    float* ssq  = (float*)(sm + 16384);              // [32]
    int*   toks = (int*)(sm + 16384 + 128);          // [32]

    const int tid  = threadIdx.x;
    const int row0 = blockIdx.x * 32;
    if (tid < 32) { toks[tid] = tok[row0 + tid] + 1; ssq[tid] = 0.f; }
    __syncthreads();

    const int wN = tid >> 6;
    const int l  = tid & 63;
    const int lr = l & 15;
    const int lg = l >> 4;
    const float* __restrict__ ebase = ent + (size_t)row0 * ENT;

    f32x4 acc[2][4];
    #pragma unroll
    for (int mf = 0; mf < 2; ++mf)
        #pragma unroll
        for (int nf = 0; nf < 4; ++nf)
            acc[mf][nf] = (f32x4){0.f, 0.f, 0.f, 0.f};

    bf16x4 pv[2][4];
    #pragma unroll
    for (int mf = 0; mf < 2; ++mf)
        #pragma unroll
        for (int reg = 0; reg < 4; ++reg) {
            const int r = mf * 16 + lg * 4 + reg;
            pv[mf][reg] = *(const bf16x4*)(Pp +
                (size_t)toks[r] * 512 + lr * 32 + wN * 8);
        }

    #pragma unroll
    for (int t = 0; t < 4; ++t) {
        bf16x8 a[2];
        #pragma unroll
        for (int mf = 0; mf < 2; ++mf) {
            const float* rp = ebase + (size_t)(mf * 16 + lr) * ENT + t * 32 + lg * 8;
            const f32x4 u0 = *(const f32x4*)rp;
            const f32x4 u1 = *(const f32x4*)(rp + 4);
            #pragma unroll
            for (int c = 0; c < 4; ++c) {
                a[mf][c]     = (__bf16)u0[c];
                a[mf][c + 4] = (__bf16)u1[c];
            }
        }
        bf16x8 wv[4];
        #pragma unroll
        for (int nf = 0; nf < 4; ++nf) {
            const int tile = t * 16 + wN * 4 + nf;
            wv[nf] = *(const bf16x8*)((const char*)Wep + (size_t)tile * 1024 + l * 16);
        }
        #pragma unroll
        for (int mf = 0; mf < 2; ++mf)
            #pragma unroll
            for (int nf = 0; nf < 4; ++nf)
                acc[mf][nf] = __builtin_amdgcn_mfma_f32_16x16x32_bf16(
                    a[mf], wv[nf], acc[mf][nf], 0, 0, 0);
    }

    float bv[4];
    #pragma unroll
    for (int nf = 0; nf < 4; ++nf) bv[nf] = bias[wN * 64 + nf * 16 + lr];
    float sq[2][4];
    #pragma unroll
    for (int mf = 0; mf < 2; ++mf)
        #pragma unroll
        for (int reg = 0; reg < 4; ++reg) {
            float s = 0.f;
            #pragma unroll
            for (int nf = 0; nf < 4; ++nf) {
                const float v = fmaxf(acc[mf][nf][reg] + (float)pv[mf][reg][nf]
                                      + bv[nf], 0.f);
                acc[mf][nf][reg] = v;
                s = fmaf(v, v, s);
            }
            sq[mf][reg] = s;
        }
    #pragma unroll
    for (int m = 1; m <= 8; m <<= 1)
        #pragma unroll
        for (int mf = 0; mf < 2; ++mf)
            #pragma unroll
            for (int reg = 0; reg < 4; ++reg)
                sq[mf][reg] += __shfl_xor(sq[mf][reg], m, 64);
    if (lr == 0) {
        #pragma unroll
        for (int mf = 0; mf < 2; ++mf)
            #pragma unroll
            for (int reg = 0; reg < 4; ++reg)
                atomicAdd(&ssq[mf * 16 + lg * 4 + reg], sq[mf][reg]);
    }
    #pragma unroll
    for (int mf = 0; mf < 2; ++mf)
        #pragma unroll
        for (int nf = 0; nf < 4; ++nf)
            #pragma unroll
            for (int reg = 0; reg < 4; ++reg) {
                const int r    = mf * 16 + lg * 4 + reg;
                const int col  = wN * 64 + nf * 16 + lr;
                const int byte = (r * 512 + col * 2) ^ ((r & 7) << 4);
                *(__bf16*)(sm + byte) = (__bf16)acc[mf][nf][reg];
            }
    __syncthreads();

    #pragma unroll
    for (int it = 0; it < 4; ++it) {
        const int idx = it * 256 + tid;
        const int row = idx >> 5, c = idx & 31;
        const int byte = (row * 512 + c * 16) ^ ((row & 7) << 4);
        bf16x8 hv = *(const bf16x8*)(sm + byte);
        const float rn = (toks[row] == 0) ? 0.f
                                          : 1.f / (sqrtf(ssq[row]) + 1e-9f);
        #pragma unroll
        for (int j = 0; j < 8; ++j) hv[j] = (__bf16)((float)hv[j] * rn);
        *(bf16x8*)(qhat + (size_t)(row0 + row) * 512 + c * 16) = hv;
    }
}

// ---------------------------------------------------------------------------
// Fused v8: 64 docs/block, 512 thr (8 waves). LDS-staged bf16 ent (cvt once),
// early P gather, K=128 transform (wave 32x64), T in LDS, sims (wave 16dx16q),
// RBF + reductions. No That round-trip.
// ---------------------------------------------------------------------------
__global__ __launch_bounds__(512) void knrm_fused2(
    const int* __restrict__ dtok,
    const float* __restrict__ dent,
    const char* __restrict__ Pp,
    const __bf16* __restrict__ Wep,
    const float* __restrict__ bias,
    const char* __restrict__ qhat,
    float* __restrict__ ksum,    // [B, NK, QLEN]
    float* __restrict__ simsum)  // [B, QLEN]
{
    __shared__ __align__(16) char sm[32768 + 2048];
    float* red  = (float*)(sm + 32768);          // [12][32]
    float* ssq  = red + 384;                     // [64]
    int*   toks = (int*)(ssq + 64);              // [64]

    const int tid = threadIdx.x;
    const int b   = blockIdx.y;
    const int d0  = blockIdx.x * 64;
    const int drow0 = b * DLEN + d0;
    const int w  = tid >> 6;
    const int l  = tid & 63;
    const int lr = l & 15;
    const int lg = l >> 4;
    const int wM = w >> 2;       // 0..1 doc half
    const int wN = w & 3;        // 0..3 col quarter

    if (tid < 384) red[tid] = 0.f;
    if (tid < 64) { toks[tid] = dtok[drow0 + tid] + 1; ssq[tid] = 0.f; }

    // stage dent -> Ab bf16 [64][128] swz at sm[0..16K)
    #pragma unroll
    for (int u = 0; u < 4; ++u) {
        const int slot = u * 512 + tid;          // 0..2047
        const int r    = slot >> 5;
        const int c4   = (slot & 31) * 4;
        const f32x4 v = *(const f32x4*)(dent + (size_t)(drow0 + r) * ENT + c4);
        bf16x4 hv;
        #pragma unroll
        for (int c = 0; c < 4; ++c) hv[c] = (__bf16)v[c];
        *(bf16x4*)(sm + ((r * 256 + c4 * 2) ^ ((r & 7) << 4))) = hv;
    }
    __syncthreads();

    // early P gather (hides L3 latency under MFMA loop)
    bf16x4 pv[2][4];
    #pragma unroll
    for (int mf = 0; mf < 2; ++mf)
        #pragma unroll
        for (int reg = 0; reg < 4; ++reg) {
            const int doc = wM * 32 + mf * 16 + lg * 4 + reg;
            pv[mf][reg] = *(const bf16x4*)(Pp +
                (size_t)toks[doc] * 512 + lr * 32 + wN * 8);
        }

    f32x4 acc[2][4];
    #pragma unroll
    for (int mf = 0; mf < 2; ++mf)
        #pragma unroll
        for (int nf = 0; nf < 4; ++nf)
            acc[mf][nf] = (f32x4){0.f, 0.f, 0.f, 0.f};

    #pragma unroll
    for (int t = 0; t < 4; ++t) {
        bf16x8 a[2];
        #pragma unroll
        for (int mf = 0; mf < 2; ++mf) {
            const int row = wM * 32 + mf * 16 + lr;
            a[mf] = *(const bf16x8*)(sm +
                ((row * 256 + t * 64 + lg * 16) ^ ((row & 7) << 4)));
        }
        bf16x8 wv[4];
        #pragma unroll
        for (int nf = 0; nf < 4; ++nf) {
            const int tile = t * 16 + wN * 4 + nf;
            wv[nf] = *(const bf16x8*)((const char*)Wep + (size_t)tile * 1024 + l * 16);
        }
        #pragma unroll
        for (int mf = 0; mf < 2; ++mf)
            #pragma unroll
            for (int nf = 0; nf < 4; ++nf)
                acc[mf][nf] = __builtin_amdgcn_mfma_f32_16x16x32_bf16(
                    a[mf], wv[nf], acc[mf][nf], 0, 0, 0);
    }
    __syncthreads();   // Ab reads done; region reusable as T

    float bv[4];
    #pragma unroll
    for (int nf = 0; nf < 4; ++nf) bv[nf] = bias[wN * 64 + nf * 16 + lr];
    float sq[2][4];
    #pragma unroll
    for (int mf = 0; mf < 2; ++mf)
        #pragma unroll
        for (int reg = 0; reg < 4; ++reg) {
            float s = 0.f;
            #pragma unroll
            for (int nf = 0; nf < 4; ++nf) {
                const float v = fmaxf(acc[mf][nf][reg] + (float)pv[mf][reg][nf]
                                      + bv[nf], 0.f);
                acc[mf][nf][reg] = v;
                s = fmaf(v, v, s);
            }
            sq[mf][reg] = s;
        }
    #pragma unroll
    for (int m = 1; m <= 8; m <<= 1)
        #pragma unroll
        for (int mf = 0; mf < 2; ++mf)
            #pragma unroll
            for (int reg = 0; reg < 4; ++reg)
                sq[mf][reg] += __shfl_xor(sq[mf][reg], m, 64);
    if (lr == 0) {
        #pragma unroll
        for (int mf = 0; mf < 2; ++mf)
            #pragma unroll
            for (int reg = 0; reg < 4; ++reg)
                atomicAdd(&ssq[wM * 32 + mf * 16 + lg * 4 + reg], sq[mf][reg]);
    }
    // write T [doc][256] bf16 swz over Ab
    #pragma unroll
    for (int mf = 0; mf < 2; ++mf)
        #pragma unroll
        for (int nf = 0; nf < 4; ++nf)
            #pragma unroll
            for (int reg = 0; reg < 4; ++reg) {
                const int doc  = wM * 32 + mf * 16 + lg * 4 + reg;
                const int col  = wN * 64 + nf * 16 + lr;
                const int byte = (doc * 512 + col * 2) ^ ((doc & 7) << 4);
                *(__bf16*)(sm + byte) = (__bf16)acc[mf][nf][reg];
            }
    __syncthreads();   // T + ssq visible

    // sims: wave -> dtile=w&3 (16 docs, M), qtile=w>>2 (16 q, N)
    const int dtile = w & 3, qtile = w >> 2;
    const int tdoc  = dtile * 16 + lr;
    const int q     = qtile * 16 + lr;
    const char* __restrict__ qb = qhat + (size_t)b * QLEN * 512;
    f32x4 s0 = (f32x4){0.f, 0.f, 0.f, 0.f};
    #pragma unroll
    for (int s = 0; s < 8; ++s) {
        const bf16x8 ta = *(const bf16x8*)(sm +
            ((tdoc * 512 + s * 64 + lg * 16) ^ ((tdoc & 7) << 4)));
        const bf16x8 qv = *(const bf16x8*)(qb + (size_t)q * 512 + s * 64 + lg * 16);
        s0 = __builtin_amdgcn_mfma_f32_16x16x32_bf16(ta, qv, s0, 0, 0, 0);
    }

    // RBF: lane = 4 docs (regs) x 1 q
    float kq[12];
    #pragma unroll
    for (int k = 0; k < 12; ++k) kq[k] = 0.f;
    #pragma unroll
    for (int reg = 0; reg < 4; ++reg) {
        const int doc = dtile * 16 + lg * 4 + reg;
        const float dnv = (toks[doc] == 0) ? 0.f
                                           : 1.f / (sqrtf(ssq[doc]) + 1e-9f);
        const float sv = s0[reg] * dnv;
        kq[11] += sv;
        #pragma unroll
        for (int k = 0; k < NK; ++k) {
            const float t = sv - d_mus[k];
            kq[k] += __expf(d_coef[k] * t * t);
        }
    }
    #pragma unroll
    for (int m = 16; m <= 32; m <<= 1)
        #pragma unroll
        for (int k = 0; k < 12; ++k)
            kq[k] += __shfl_xor(kq[k], m, 64);
    if (lg == 0) {
        #pragma unroll
        for (int k = 0; k < 12; ++k)
            atomicAdd(&red[k * 32 + q], kq[k]);
    }
    __syncthreads();

    for (int i = tid; i < 384; i += 512) {
        const int k = i >> 5, qq = i & 31;
        if (k < NK) atomicAdd(&ksum[((size_t)b * NK + k) * QLEN + qq], red[i]);
        else        atomicAdd(&simsum[b * QLEN + qq], red[i]);
    }
}

// ---------------------------------------------------------------------------
__global__ __launch_bounds__(384) void knrm_final(
    const float* __restrict__ ksum,
    const float* __restrict__ simsum,
    const float* __restrict__ Wc, const float* __restrict__ bc,
    float* __restrict__ out)
{
    __shared__ float redq[NK][QLEN];
    __shared__ float res[NK];
    const int b = blockIdx.x;
    const int t = threadIdx.x;
    if (t < NK * QLEN) {
        const int k = t >> 5;
        const int q = t & 31;
        const float ms = simsum[b * QLEN + q];
        redq[k][q] = (ms != 0.0f)
            ? logf(ksum[((size_t)b * NK + k) * QLEN + q] + 1e-6f)
            : 0.0f;
    }
    __syncthreads();
    if (t < NK) {
        float s = 0.f;
        for (int q = 0; q < QLEN; ++q) s += redq[t][q];
        res[t] = s;
    }
    __syncthreads();
    if (t == 0) {
        float s = bc[0];
        for (int k = 0; k < NK; ++k) s += res[k] * Wc[k];
        out[b] = s;
    }
}

// ---------------------------------------------------------------------------
extern "C" void kernel_launch(void* const* d_in, const int* in_sizes, int n_in,
                              void* d_out, int out_size, void* d_ws, size_t ws_size,
                              hipStream_t stream)
{
    (void)in_sizes; (void)n_in; (void)out_size; (void)ws_size;
    const int*   qtok = (const int*)d_in[0];
    const int*   dtok = (const int*)d_in[1];
    const float* qent = (const float*)d_in[2];
    const float* dent = (const float*)d_in[3];
    const float* emb  = (const float*)d_in[4];
    const float* Wt   = (const float*)d_in[5];
    const float* bt   = (const float*)d_in[6];
    const float* We   = (const float*)d_in[7];
    const float* be   = (const float*)d_in[8];
    const float* Wc   = (const float*)d_in[9];
    const float* bc   = (const float*)d_in[10];
    float* out = (float*)d_out;

    char* ws = (char*)d_ws;
    const size_t off_qhat = 0;                               // 1,048,576
    const size_t off_Wtp  = off_qhat + 1048576;              //   163,840
    const size_t off_Wep  = off_Wtp  + 163840;               //    65,536
    const size_t off_bias = off_Wep  + 65536;                //     1,024
    const size_t off_ksum = off_bias + 1024;                 //    90,112
    const size_t off_sim  = off_ksum + 90112;                //     8,192
    const size_t off_P    = off_sim  + 8192;                 // 25,600,000

    char*   qhat  = ws + off_qhat;
    __bf16* Wtp   = (__bf16*)(ws + off_Wtp);
    __bf16* Wep   = (__bf16*)(ws + off_Wep);
    float*  bias  = (float*)(ws + off_bias);
    float*  ksum  = (float*)(ws + off_ksum);
    float*  simsum= (float*)(ws + off_sim);
    char*   P     = ws + off_P;

    hipMemsetAsync(ksum, 0, (size_t)(90112 + 8192), stream);

    knrm_wpack<<<dim3(56), dim3(256), 0, stream>>>(Wt, We, bt, be, Wtp, Wep, bias);
    knrm_pgemm<<<dim3((VOCAB + 63) / 64), dim3(256), 0, stream>>>(emb, Wtp, P);
    knrm_qtrans<<<dim3(64), dim3(256), 0, stream>>>(
        qtok, qent, P, Wep, bias, qhat);
    knrm_fused2<<<dim3(DLEN / 64, B_), dim3(512), 0, stream>>>(
        dtok, dent, P, Wep, bias, qhat, ksum, simsum);
    knrm_final<<<dim3(B_), dim3(384), 0, stream>>>(ksum, simsum, Wc, bc, out);
}

// Round 9
// 105.997 us; speedup vs baseline: 1.3972x; 1.0070x over previous
//
#include <hip/hip_runtime.h>
#include <math.h>

#define B_    64
#define QLEN  32
#define DLEN  2048
#define WORD  300
#define ENT   128
#define AD    256
#define NK    11
#define VOCAB 50000

typedef __bf16 bf16x8 __attribute__((ext_vector_type(8)));
typedef __bf16 bf16x4 __attribute__((ext_vector_type(4)));
typedef float  f32x4  __attribute__((ext_vector_type(4)));

static __device__ const float d_mus[NK] =
    {-0.9f,-0.7f,-0.5f,-0.3f,-0.1f,0.1f,0.3f,0.5f,0.7f,0.9f,1.0f};
static __device__ const float d_coef[NK] =
    {-50.f,-50.f,-50.f,-50.f,-50.f,-50.f,-50.f,-50.f,-50.f,-50.f,-500000.f};

// ---------------------------------------------------------------------------
// W-pack: Wtp (K=320 pad, 160 tiles) + Wep (K=128, 64 tiles), MFMA-B order.
// tile = 64 lanes x 16B; lane l elem j: B[k=s*32+(l>>4)*8+j][col=nb*16+(l&15)]
// ---------------------------------------------------------------------------
__global__ __launch_bounds__(256) void knrm_wpack(
    const float* __restrict__ Wt, const float* __restrict__ We,
    const float* __restrict__ bt, const float* __restrict__ be,
    __bf16* __restrict__ Wtp, __bf16* __restrict__ Wep,
    float* __restrict__ bias)
{
    const int idx = blockIdx.x * 256 + threadIdx.x;   // 0..14335
    if (idx < AD) bias[idx] = bt[idx] + be[idx];
    const int tile = idx >> 6, l = idx & 63;
    bf16x8 h;
    if (tile < 160) {
        const int s = tile >> 4, nb = tile & 15;
        const int col = nb * 16 + (l & 15);
        const int k0  = s * 32 + (l >> 4) * 8;
        #pragma unroll
        for (int j = 0; j < 8; ++j) {
            const int k = k0 + j;
            h[j] = (__bf16)((k < WORD) ? Wt[(size_t)k * AD + col] : 0.f);
        }
        *(bf16x8*)((char*)Wtp + (size_t)idx * 16) = h;
    } else {
        const int t2 = tile - 160;
        const int s = t2 >> 4, nb = t2 & 15;
        const int col = nb * 16 + (l & 15);
        const int k0  = s * 32 + (l >> 4) * 8;
        #pragma unroll
        for (int j = 0; j < 8; ++j)
            h[j] = (__bf16)We[(size_t)(k0 + j) * AD + col];
        *(bf16x8*)((char*)Wep + (size_t)(idx - 10240) * 16) = h;
    }
}

// ---------------------------------------------------------------------------
// P-GEMM (LDS-staged A, cvt once): P[v] = emb[v] @ Wt, bf16, permuted rows:
// pos(col) = (col&15)*16 + (col>>6)*4 + ((col>>4)&3), 512 B/row.
// ---------------------------------------------------------------------------
__global__ __launch_bounds__(256) void knrm_pgemm(
    const float* __restrict__ emb,
    const __bf16* __restrict__ Wtp,
    char* __restrict__ P)
{
    __shared__ __align__(16) char sm[40960];   // A [64][320] bf16 swizzled
    const int tid = threadIdx.x;
    const int v0  = blockIdx.x * 64;

    #pragma unroll
    for (int u = 0; u < 20; ++u) {
        const int idx  = u * 256 + tid;        // 0..5119
        const int r    = idx / 80;
        const int slot = idx - r * 80;
        const int k    = slot * 4;
        f32x4 v = (f32x4){0.f, 0.f, 0.f, 0.f};
        if (k < WORD && v0 + r < VOCAB)
            v = *(const f32x4*)(emb + (size_t)(v0 + r) * WORD + k);
        bf16x4 hv;
        #pragma unroll
        for (int c = 0; c < 4; ++c) hv[c] = (__bf16)v[c];
        *(bf16x4*)(sm + ((r * 640 + slot * 8) ^ ((r & 7) << 4))) = hv;
    }
    __syncthreads();

    const int w  = tid >> 6;
    const int l  = tid & 63;
    const int lr = l & 15;
    const int lg = l >> 4;

    f32x4 acc[4][4];
    #pragma unroll
    for (int mf = 0; mf < 4; ++mf)
        #pragma unroll
        for (int nf = 0; nf < 4; ++nf)
            acc[mf][nf] = (f32x4){0.f, 0.f, 0.f, 0.f};

    #pragma unroll
    for (int t = 0; t < 10; ++t) {
        bf16x8 a[4];
        #pragma unroll
        for (int mf = 0; mf < 4; ++mf) {
            const int row = mf * 16 + lr;
            a[mf] = *(const bf16x8*)(sm +
                ((row * 640 + t * 64 + lg * 16) ^ ((row & 7) << 4)));
        }
        bf16x8 wv[4];
        #pragma unroll
        for (int nf = 0; nf < 4; ++nf) {
            const int tile = t * 16 + w * 4 + nf;
            wv[nf] = *(const bf16x8*)((const char*)Wtp + (size_t)tile * 1024 + l * 16);
        }
        #pragma unroll
        for (int mf = 0; mf < 4; ++mf)
            #pragma unroll
            for (int nf = 0; nf < 4; ++nf)
                acc[mf][nf] = __builtin_amdgcn_mfma_f32_16x16x32_bf16(
                    a[mf], wv[nf], acc[mf][nf], 0, 0, 0);
    }

    #pragma unroll
    for (int mf = 0; mf < 4; ++mf)
        #pragma unroll
        for (int reg = 0; reg < 4; ++reg) {
            const int v = v0 + mf * 16 + lg * 4 + reg;
            if (v < VOCAB) {
                bf16x4 h;
                #pragma unroll
                for (int nf = 0; nf < 4; ++nf) h[nf] = (__bf16)acc[mf][nf][reg];
                *(bf16x4*)(P + (size_t)v * 512 + lr * 32 + w * 8) = h;
            }
        }
}

// ---------------------------------------------------------------------------
// Query transform: 32 rows/block, grid 64. relu(P[tok]+qent@We+bias),
// normalize, zero padded rows; write qhat row-major bf16 [2048][256].
// ---------------------------------------------------------------------------
__global__ __launch_bounds__(256) void knrm_qtrans(
    const int* __restrict__ tok,
    const float* __restrict__ ent,
    const char* __restrict__ Pp,
    const __bf16* __restrict__ Wep,
    const float* __restrict__ bias,
    char* __restrict__ qhat)
{
    __shared__ __align__(16) char sm[16384 + 256];   // T [32][256] bf16 swz
    float* ssq  = (float*)(sm + 16384);              // [32]
    int*   toks = (int*)(sm + 16384 + 128);          // [32]

    const int tid  = threadIdx.x;
    const int row0 = blockIdx.x * 32;
    if (tid < 32) { toks[tid] = tok[row0 + tid] + 1; ssq[tid] = 0.f; }
    __syncthreads();

    const int wN = tid >> 6;
    const int l  = tid & 63;
    const int lr = l & 15;
    const int lg = l >> 4;
    const float* __restrict__ ebase = ent + (size_t)row0 * ENT;

    f32x4 acc[2][4];
    #pragma unroll
    for (int mf = 0; mf < 2; ++mf)
        #pragma unroll
        for (int nf = 0; nf < 4; ++nf)
            acc[mf][nf] = (f32x4){0.f, 0.f, 0.f, 0.f};

    bf16x4 pv[2][4];
    #pragma unroll
    for (int mf = 0; mf < 2; ++mf)
        #pragma unroll
        for (int reg = 0; reg < 4; ++reg) {
            const int r = mf * 16 + lg * 4 + reg;
            pv[mf][reg] = *(const bf16x4*)(Pp +
                (size_t)toks[r] * 512 + lr * 32 + wN * 8);
        }

    #pragma unroll
    for (int t = 0; t < 4; ++t) {
        bf16x8 a[2];
        #pragma unroll
        for (int mf = 0; mf < 2; ++mf) {
            const float* rp = ebase + (size_t)(mf * 16 + lr) * ENT + t * 32 + lg * 8;
            const f32x4 u0 = *(const f32x4*)rp;
            const f32x4 u1 = *(const f32x4*)(rp + 4);
            #pragma unroll
            for (int c = 0; c < 4; ++c) {
                a[mf][c]     = (__bf16)u0[c];
                a[mf][c + 4] = (__bf16)u1[c];
            }
        }
        bf16x8 wv[4];
        #pragma unroll
        for (int nf = 0; nf < 4; ++nf) {
            const int tile = t * 16 + wN * 4 + nf;
            wv[nf] = *(const bf16x8*)((const char*)Wep + (size_t)tile * 1024 + l * 16);
        }
        #pragma unroll
        for (int mf = 0; mf < 2; ++mf)
            #pragma unroll
            for (int nf = 0; nf < 4; ++nf)
                acc[mf][nf] = __builtin_amdgcn_mfma_f32_16x16x32_bf16(
                    a[mf], wv[nf], acc[mf][nf], 0, 0, 0);
    }

    float bv[4];
    #pragma unroll
    for (int nf = 0; nf < 4; ++nf) bv[nf] = bias[wN * 64 + nf * 16 + lr];
    float sq[2][4];
    #pragma unroll
    for (int mf = 0; mf < 2; ++mf)
        #pragma unroll
        for (int reg = 0; reg < 4; ++reg) {
            float s = 0.f;
            #pragma unroll
            for (int nf = 0; nf < 4; ++nf) {
                const float v = fmaxf(acc[mf][nf][reg] + (float)pv[mf][reg][nf]
                                      + bv[nf], 0.f);
                acc[mf][nf][reg] = v;
                s = fmaf(v, v, s);
            }
            sq[mf][reg] = s;
        }
    #pragma unroll
    for (int m = 1; m <= 8; m <<= 1)
        #pragma unroll
        for (int mf = 0; mf < 2; ++mf)
            #pragma unroll
            for (int reg = 0; reg < 4; ++reg)
                sq[mf][reg] += __shfl_xor(sq[mf][reg], m, 64);
    if (lr == 0) {
        #pragma unroll
        for (int mf = 0; mf < 2; ++mf)
            #pragma unroll
            for (int reg = 0; reg < 4; ++reg)
                atomicAdd(&ssq[mf * 16 + lg * 4 + reg], sq[mf][reg]);
    }
    #pragma unroll
    for (int mf = 0; mf < 2; ++mf)
        #pragma unroll
        for (int nf = 0; nf < 4; ++nf)
            #pragma unroll
            for (int reg = 0; reg < 4; ++reg) {
                const int r    = mf * 16 + lg * 4 + reg;
                const int col  = wN * 64 + nf * 16 + lr;
                const int byte = (r * 512 + col * 2) ^ ((r & 7) << 4);
                *(__bf16*)(sm + byte) = (__bf16)acc[mf][nf][reg];
            }
    __syncthreads();

    #pragma unroll
    for (int it = 0; it < 4; ++it) {
        const int idx = it * 256 + tid;
        const int row = idx >> 5, c = idx & 31;
        const int byte = (row * 512 + c * 16) ^ ((row & 7) << 4);
        bf16x8 hv = *(const bf16x8*)(sm + byte);
        const float rn = (toks[row] == 0) ? 0.f
                                          : 1.f / (sqrtf(ssq[row]) + 1e-9f);
        #pragma unroll
        for (int j = 0; j < 8; ++j) hv[j] = (__bf16)((float)hv[j] * rn);
        *(bf16x8*)(qhat + (size_t)(row0 + row) * 512 + c * 16) = hv;
    }
}

// ---------------------------------------------------------------------------
// Fused v9: 32 docs/block, 256 thr (4 waves). Small blocks -> 8 blocks/CU
// residency ceiling; per-wave work identical to v8. T swizzle widened to
// (doc&15)<<4 (conflict-free reads, 2-way writes).
// ---------------------------------------------------------------------------
__global__ __launch_bounds__(256) void knrm_fused2(
    const int* __restrict__ dtok,
    const float* __restrict__ dent,
    const char* __restrict__ Pp,
    const __bf16* __restrict__ Wep,
    const float* __restrict__ bias,
    const char* __restrict__ qhat,
    float* __restrict__ ksum,    // [B, NK, QLEN]
    float* __restrict__ simsum)  // [B, QLEN]
{
    __shared__ __align__(16) char sm[16384 + 2048];
    float* red  = (float*)(sm + 16384);          // [12][32]
    float* ssq  = red + 384;                     // [32]
    int*   toks = (int*)(ssq + 32);              // [32]

    const int tid = threadIdx.x;
    const int b   = blockIdx.y;
    const int d0  = blockIdx.x * 32;
    const int drow0 = b * DLEN + d0;
    const int w  = tid >> 6;     // 0..3 : col quarter (transform)
    const int l  = tid & 63;
    const int lr = l & 15;
    const int lg = l >> 4;

    for (int i = tid; i < 416; i += 256) red[i] = 0.f;   // red + ssq
    if (tid < 32) toks[tid] = dtok[drow0 + tid] + 1;

    // stage dent -> Ab bf16 [32][128] swz at sm[0..8K)
    #pragma unroll
    for (int u = 0; u < 4; ++u) {
        const int slot = u * 256 + tid;          // 0..1023
        const int r    = slot >> 5;
        const int c4   = (slot & 31) * 4;
        const f32x4 v = *(const f32x4*)(dent + (size_t)(drow0 + r) * ENT + c4);
        bf16x4 hv;
        #pragma unroll
        for (int c = 0; c < 4; ++c) hv[c] = (__bf16)v[c];
        *(bf16x4*)(sm + ((r * 256 + c4 * 2) ^ ((r & 7) << 4))) = hv;
    }
    __syncthreads();

    // early P gather (L3 latency hides under MFMA loop)
    bf16x4 pv[2][4];
    #pragma unroll
    for (int mf = 0; mf < 2; ++mf)
        #pragma unroll
        for (int reg = 0; reg < 4; ++reg) {
            const int doc = mf * 16 + lg * 4 + reg;
            pv[mf][reg] = *(const bf16x4*)(Pp +
                (size_t)toks[doc] * 512 + lr * 32 + w * 8);
        }

    f32x4 acc[2][4];
    #pragma unroll
    for (int mf = 0; mf < 2; ++mf)
        #pragma unroll
        for (int nf = 0; nf < 4; ++nf)
            acc[mf][nf] = (f32x4){0.f, 0.f, 0.f, 0.f};

    #pragma unroll
    for (int t = 0; t < 4; ++t) {
        bf16x8 a[2];
        #pragma unroll
        for (int mf = 0; mf < 2; ++mf) {
            const int row = mf * 16 + lr;
            a[mf] = *(const bf16x8*)(sm +
                ((row * 256 + t * 64 + lg * 16) ^ ((row & 7) << 4)));
        }
        bf16x8 wv[4];
        #pragma unroll
        for (int nf = 0; nf < 4; ++nf) {
            const int tile = t * 16 + w * 4 + nf;
            wv[nf] = *(const bf16x8*)((const char*)Wep + (size_t)tile * 1024 + l * 16);
        }
        #pragma unroll
        for (int mf = 0; mf < 2; ++mf)
            #pragma unroll
            for (int nf = 0; nf < 4; ++nf)
                acc[mf][nf] = __builtin_amdgcn_mfma_f32_16x16x32_bf16(
                    a[mf], wv[nf], acc[mf][nf], 0, 0, 0);
    }
    __syncthreads();   // Ab reads done; region reusable as T

    float bv[4];
    #pragma unroll
    for (int nf = 0; nf < 4; ++nf) bv[nf] = bias[w * 64 + nf * 16 + lr];
    float sq[2][4];
    #pragma unroll
    for (int mf = 0; mf < 2; ++mf)
        #pragma unroll
        for (int reg = 0; reg < 4; ++reg) {
            float s = 0.f;
            #pragma unroll
            for (int nf = 0; nf < 4; ++nf) {
                const float v = fmaxf(acc[mf][nf][reg] + (float)pv[mf][reg][nf]
                                      + bv[nf], 0.f);
                acc[mf][nf][reg] = v;
                s = fmaf(v, v, s);
            }
            sq[mf][reg] = s;
        }
    #pragma unroll
    for (int m = 1; m <= 8; m <<= 1)
        #pragma unroll
        for (int mf = 0; mf < 2; ++mf)
            #pragma unroll
            for (int reg = 0; reg < 4; ++reg)
                sq[mf][reg] += __shfl_xor(sq[mf][reg], m, 64);
    if (lr == 0) {
        #pragma unroll
        for (int mf = 0; mf < 2; ++mf)
            #pragma unroll
            for (int reg = 0; reg < 4; ++reg)
                atomicAdd(&ssq[mf * 16 + lg * 4 + reg], sq[mf][reg]);
    }
    // write T [doc][256] bf16: byte = doc*512 + (col*2 ^ ((doc&15)<<4))
    #pragma unroll
    for (int mf = 0; mf < 2; ++mf)
        #pragma unroll
        for (int nf = 0; nf < 4; ++nf)
            #pragma unroll
            for (int reg = 0; reg < 4; ++reg) {
                const int doc  = mf * 16 + lg * 4 + reg;
                const int col  = w * 64 + nf * 16 + lr;
                const int byte = doc * 512 + ((col * 2) ^ ((doc & 15) << 4));
                *(__bf16*)(sm + byte) = (__bf16)acc[mf][nf][reg];
            }
    __syncthreads();   // T + ssq visible

    // sims: wave -> dtile=w&1 (16 docs, M), qtile=w>>1 (16 q, N)
    const int dtile = w & 1, qtile = w >> 1;
    const int tdoc  = dtile * 16 + lr;
    const int q     = qtile * 16 + lr;
    const char* __restrict__ qb = qhat + (size_t)b * QLEN * 512;
    f32x4 s0 = (f32x4){0.f, 0.f, 0.f, 0.f};
    #pragma unroll
    for (int s = 0; s < 8; ++s) {
        const bf16x8 ta = *(const bf16x8*)(sm +
            (tdoc * 512 + ((s * 64 + lg * 16) ^ ((tdoc & 15) << 4))));
        const bf16x8 qv = *(const bf16x8*)(qb + (size_t)q * 512 + s * 64 + lg * 16);
        s0 = __builtin_amdgcn_mfma_f32_16x16x32_bf16(ta, qv, s0, 0, 0, 0);
    }

    // RBF: lane = 4 docs (regs) x 1 q
    float kq[12];
    #pragma unroll
    for (int k = 0; k < 12; ++k) kq[k] = 0.f;
    #pragma unroll
    for (int reg = 0; reg < 4; ++reg) {
        const int doc = dtile * 16 + lg * 4 + reg;
        const float dnv = (toks[doc] == 0) ? 0.f
                                           : 1.f / (sqrtf(ssq[doc]) + 1e-9f);
        const float sv = s0[reg] * dnv;
        kq[11] += sv;
        #pragma unroll
        for (int k = 0; k < NK; ++k) {
            const float t = sv - d_mus[k];
            kq[k] += __expf(d_coef[k] * t * t);
        }
    }
    #pragma unroll
    for (int m = 16; m <= 32; m <<= 1)
        #pragma unroll
        for (int k = 0; k < 12; ++k)
            kq[k] += __shfl_xor(kq[k], m, 64);
    if (lg == 0) {
        #pragma unroll
        for (int k = 0; k < 12; ++k)
            atomicAdd(&red[k * 32 + q], kq[k]);
    }
    __syncthreads();

    for (int i = tid; i < 384; i += 256) {
        const int k = i >> 5, qq = i & 31;
        if (k < NK) atomicAdd(&ksum[((size_t)b * NK + k) * QLEN + qq], red[i]);
        else        atomicAdd(&simsum[b * QLEN + qq], red[i]);
    }
}

// ---------------------------------------------------------------------------
__global__ __launch_bounds__(384) void knrm_final(
    const float* __restrict__ ksum,
    const float* __restrict__ simsum,
    const float* __restrict__ Wc, const float* __restrict__ bc,
    float* __restrict__ out)
{
    __shared__ float redq[NK][QLEN];
    __shared__ float res[NK];
    const int b = blockIdx.x;
    const int t = threadIdx.x;
    if (t < NK * QLEN) {
        const int k = t >> 5;
        const int q = t & 31;
        const float ms = simsum[b * QLEN + q];
        redq[k][q] = (ms != 0.0f)
            ? logf(ksum[((size_t)b * NK + k) * QLEN + q] + 1e-6f)
            : 0.0f;
    }
    __syncthreads();
    if (t < NK) {
        float s = 0.f;
        for (int q = 0; q < QLEN; ++q) s += redq[t][q];
        res[t] = s;
    }
    __syncthreads();
    if (t == 0) {
        float s = bc[0];
        for (int k = 0; k < NK; ++k) s += res[k] * Wc[k];
        out[b] = s;
    }
}

// ---------------------------------------------------------------------------
extern "C" void kernel_launch(void* const* d_in, const int* in_sizes, int n_in,
                              void* d_out, int out_size, void* d_ws, size_t ws_size,
                              hipStream_t stream)
{
    (void)in_sizes; (void)n_in; (void)out_size; (void)ws_size;
    const int*   qtok = (const int*)d_in[0];
    const int*   dtok = (const int*)d_in[1];
    const float* qent = (const float*)d_in[2];
    const float* dent = (const float*)d_in[3];
    const float* emb  = (const float*)d_in[4];
    const float* Wt   = (const float*)d_in[5];
    const float* bt   = (const float*)d_in[6];
    const float* We   = (const float*)d_in[7];
    const float* be   = (const float*)d_in[8];
    const float* Wc   = (const float*)d_in[9];
    const float* bc   = (const float*)d_in[10];
    float* out = (float*)d_out;

    char* ws = (char*)d_ws;
    const size_t off_qhat = 0;                               // 1,048,576
    const size_t off_Wtp  = off_qhat + 1048576;              //   163,840
    const size_t off_Wep  = off_Wtp  + 163840;               //    65,536
    const size_t off_bias = off_Wep  + 65536;                //     1,024
    const size_t off_ksum = off_bias + 1024;                 //    90,112
    const size_t off_sim  = off_ksum + 90112;                //     8,192
    const size_t off_P    = off_sim  + 8192;                 // 25,600,000

    char*   qhat  = ws + off_qhat;
    __bf16* Wtp   = (__bf16*)(ws + off_Wtp);
    __bf16* Wep   = (__bf16*)(ws + off_Wep);
    float*  bias  = (float*)(ws + off_bias);
    float*  ksum  = (float*)(ws + off_ksum);
    float*  simsum= (float*)(ws + off_sim);
    char*   P     = ws + off_P;

    hipMemsetAsync(ksum, 0, (size_t)(90112 + 8192), stream);

    knrm_wpack<<<dim3(56), dim3(256), 0, stream>>>(Wt, We, bt, be, Wtp, Wep, bias);
    knrm_pgemm<<<dim3((VOCAB + 63) / 64), dim3(256), 0, stream>>>(emb, Wtp, P);
    knrm_qtrans<<<dim3(64), dim3(256), 0, stream>>>(
        qtok, qent, P, Wep, bias, qhat);
    knrm_fused2<<<dim3(DLEN / 32, B_), dim3(256), 0, stream>>>(
        dtok, dent, P, Wep, bias, qhat, ksum, simsum);
    knrm_final<<<dim3(B_), dim3(384), 0, stream>>>(ksum, simsum, Wc, bc, out);
}

// Round 10
// 90.524 us; speedup vs baseline: 1.6360x; 1.1709x over previous
//
#include <hip/hip_runtime.h>
#include <math.h>

#define B_    64
#define QLEN  32
#define DLEN  2048
#define WORD  300
#define ENT   128
#define AD    256
#define NK    11
#define VOCAB 50000

typedef __bf16 bf16x8 __attribute__((ext_vector_type(8)));
typedef __bf16 bf16x4 __attribute__((ext_vector_type(4)));
typedef float  f32x4  __attribute__((ext_vector_type(4)));

// ---------------------------------------------------------------------------
// W-pack: Wtp (K=320 pad, 160 tiles) + Wep (K=128, 64 tiles), MFMA-B order.
// tile = 64 lanes x 16B; lane l elem j: B[k=s*32+(l>>4)*8+j][col=nb*16+(l&15)]
// ---------------------------------------------------------------------------
__global__ __launch_bounds__(256) void knrm_wpack(
    const float* __restrict__ Wt, const float* __restrict__ We,
    const float* __restrict__ bt, const float* __restrict__ be,
    __bf16* __restrict__ Wtp, __bf16* __restrict__ Wep,
    float* __restrict__ bias)
{
    const int idx = blockIdx.x * 256 + threadIdx.x;   // 0..14335
    if (idx < AD) bias[idx] = bt[idx] + be[idx];
    const int tile = idx >> 6, l = idx & 63;
    bf16x8 h;
    if (tile < 160) {
        const int s = tile >> 4, nb = tile & 15;
        const int col = nb * 16 + (l & 15);
        const int k0  = s * 32 + (l >> 4) * 8;
        #pragma unroll
        for (int j = 0; j < 8; ++j) {
            const int k = k0 + j;
            h[j] = (__bf16)((k < WORD) ? Wt[(size_t)k * AD + col] : 0.f);
        }
        *(bf16x8*)((char*)Wtp + (size_t)idx * 16) = h;
    } else {
        const int t2 = tile - 160;
        const int s = t2 >> 4, nb = t2 & 15;
        const int col = nb * 16 + (l & 15);
        const int k0  = s * 32 + (l >> 4) * 8;
        #pragma unroll
        for (int j = 0; j < 8; ++j)
            h[j] = (__bf16)We[(size_t)(k0 + j) * AD + col];
        *(bf16x8*)((char*)Wep + (size_t)(idx - 10240) * 16) = h;
    }
}

// ---------------------------------------------------------------------------
// P-GEMM: P[v] = emb[v] @ Wt, bf16, permuted rows (512B):
// offset(col) = (col>>6)*128 + (col&15)*8 + ((col>>4)&3)*2  -> coalesced store
// ---------------------------------------------------------------------------
__global__ __launch_bounds__(256) void knrm_pgemm(
    const float* __restrict__ emb,
    const __bf16* __restrict__ Wtp,
    char* __restrict__ P)
{
    __shared__ __align__(16) char sm[40960];   // A [64][320] bf16 swizzled
    const int tid = threadIdx.x;
    const int v0  = blockIdx.x * 64;

    #pragma unroll
    for (int u = 0; u < 20; ++u) {
        const int idx  = u * 256 + tid;        // 0..5119
        const int r    = idx / 80;
        const int slot = idx - r * 80;
        const int k    = slot * 4;
        f32x4 v = (f32x4){0.f, 0.f, 0.f, 0.f};
        if (k < WORD && v0 + r < VOCAB)
            v = *(const f32x4*)(emb + (size_t)(v0 + r) * WORD + k);
        bf16x4 hv;
        #pragma unroll
        for (int c = 0; c < 4; ++c) hv[c] = (__bf16)v[c];
        *(bf16x4*)(sm + ((r * 640 + slot * 8) ^ ((r & 7) << 4))) = hv;
    }
    __syncthreads();

    const int w  = tid >> 6;
    const int l  = tid & 63;
    const int lr = l & 15;
    const int lg = l >> 4;

    f32x4 acc[4][4];
    #pragma unroll
    for (int mf = 0; mf < 4; ++mf)
        #pragma unroll
        for (int nf = 0; nf < 4; ++nf)
            acc[mf][nf] = (f32x4){0.f, 0.f, 0.f, 0.f};

    #pragma unroll
    for (int t = 0; t < 10; ++t) {
        bf16x8 a[4];
        #pragma unroll
        for (int mf = 0; mf < 4; ++mf) {
            const int row = mf * 16 + lr;
            a[mf] = *(const bf16x8*)(sm +
                ((row * 640 + t * 64 + lg * 16) ^ ((row & 7) << 4)));
        }
        bf16x8 wv[4];
        #pragma unroll
        for (int nf = 0; nf < 4; ++nf) {
            const int tile = t * 16 + w * 4 + nf;
            wv[nf] = *(const bf16x8*)((const char*)Wtp + (size_t)tile * 1024 + l * 16);
        }
        #pragma unroll
        for (int mf = 0; mf < 4; ++mf)
            #pragma unroll
            for (int nf = 0; nf < 4; ++nf)
                acc[mf][nf] = __builtin_amdgcn_mfma_f32_16x16x32_bf16(
                    a[mf], wv[nf], acc[mf][nf], 0, 0, 0);
    }

    #pragma unroll
    for (int mf = 0; mf < 4; ++mf)
        #pragma unroll
        for (int reg = 0; reg < 4; ++reg) {
            const int v = v0 + mf * 16 + lg * 4 + reg;
            if (v < VOCAB) {
                bf16x4 h;
                #pragma unroll
                for (int nf = 0; nf < 4; ++nf) h[nf] = (__bf16)acc[mf][nf][reg];
                *(bf16x4*)(P + (size_t)v * 512 + w * 128 + lr * 8) = h;
            }
        }
}

// ---------------------------------------------------------------------------
// Query transform: 32 rows (1 batch)/block, grid 64. relu(P[tok]+qent@We+b),
// normalize, zero padded rows; write qhatF in B-FRAGMENT TILE order:
// qhatF[b][tile = s*2+qt][lane]*16B, tile value = qhat[qt*16+(l&15)][s*32+(l>>4)*8..+8]
// ---------------------------------------------------------------------------
__global__ __launch_bounds__(256) void knrm_qtrans(
    const int* __restrict__ tok,
    const float* __restrict__ ent,
    const char* __restrict__ Pp,
    const __bf16* __restrict__ Wep,
    const float* __restrict__ bias,
    char* __restrict__ qhatF)
{
    __shared__ __align__(16) char sm[16384 + 256];   // T [32][256] bf16 swz
    float* ssq  = (float*)(sm + 16384);              // [32]
    int*   toks = (int*)(sm + 16384 + 128);          // [32]

    const int tid  = threadIdx.x;
    const int row0 = blockIdx.x * 32;
    if (tid < 32) { toks[tid] = tok[row0 + tid] + 1; ssq[tid] = 0.f; }
    __syncthreads();

    const int wN = tid >> 6;
    const int l  = tid & 63;
    const int lr = l & 15;
    const int lg = l >> 4;
    const float* __restrict__ ebase = ent + (size_t)row0 * ENT;

    f32x4 acc[2][4];
    #pragma unroll
    for (int mf = 0; mf < 2; ++mf)
        #pragma unroll
        for (int nf = 0; nf < 4; ++nf)
            acc[mf][nf] = (f32x4){0.f, 0.f, 0.f, 0.f};

    bf16x4 pv[2][4];
    #pragma unroll
    for (int mf = 0; mf < 2; ++mf)
        #pragma unroll
        for (int reg = 0; reg < 4; ++reg) {
            const int r = mf * 16 + lg * 4 + reg;
            pv[mf][reg] = *(const bf16x4*)(Pp +
                (size_t)toks[r] * 512 + wN * 128 + lr * 8);
        }

    #pragma unroll
    for (int t = 0; t < 4; ++t) {
        bf16x8 a[2];
        #pragma unroll
        for (int mf = 0; mf < 2; ++mf) {
            const float* rp = ebase + (size_t)(mf * 16 + lr) * ENT + t * 32 + lg * 8;
            const f32x4 u0 = *(const f32x4*)rp;
            const f32x4 u1 = *(const f32x4*)(rp + 4);
            #pragma unroll
            for (int c = 0; c < 4; ++c) {
                a[mf][c]     = (__bf16)u0[c];
                a[mf][c + 4] = (__bf16)u1[c];
            }
        }
        bf16x8 wv[4];
        #pragma unroll
        for (int nf = 0; nf < 4; ++nf) {
            const int tile = t * 16 + wN * 4 + nf;
            wv[nf] = *(const bf16x8*)((const char*)Wep + (size_t)tile * 1024 + l * 16);
        }
        #pragma unroll
        for (int mf = 0; mf < 2; ++mf)
            #pragma unroll
            for (int nf = 0; nf < 4; ++nf)
                acc[mf][nf] = __builtin_amdgcn_mfma_f32_16x16x32_bf16(
                    a[mf], wv[nf], acc[mf][nf], 0, 0, 0);
    }

    float bv[4];
    #pragma unroll
    for (int nf = 0; nf < 4; ++nf) bv[nf] = bias[wN * 64 + nf * 16 + lr];
    float sq[2][4];
    #pragma unroll
    for (int mf = 0; mf < 2; ++mf)
        #pragma unroll
        for (int reg = 0; reg < 4; ++reg) {
            float s = 0.f;
            #pragma unroll
            for (int nf = 0; nf < 4; ++nf) {
                const float v = fmaxf(acc[mf][nf][reg] + (float)pv[mf][reg][nf]
                                      + bv[nf], 0.f);
                acc[mf][nf][reg] = v;
                s = fmaf(v, v, s);
            }
            sq[mf][reg] = s;
        }
    #pragma unroll
    for (int m = 1; m <= 8; m <<= 1)
        #pragma unroll
        for (int mf = 0; mf < 2; ++mf)
            #pragma unroll
            for (int reg = 0; reg < 4; ++reg)
                sq[mf][reg] += __shfl_xor(sq[mf][reg], m, 64);
    if (lr == 0) {
        #pragma unroll
        for (int mf = 0; mf < 2; ++mf)
            #pragma unroll
            for (int reg = 0; reg < 4; ++reg)
                atomicAdd(&ssq[mf * 16 + lg * 4 + reg], sq[mf][reg]);
    }
    #pragma unroll
    for (int mf = 0; mf < 2; ++mf)
        #pragma unroll
        for (int nf = 0; nf < 4; ++nf)
            #pragma unroll
            for (int reg = 0; reg < 4; ++reg) {
                const int r    = mf * 16 + lg * 4 + reg;
                const int col  = wN * 64 + nf * 16 + lr;
                const int byte = (r * 512 + col * 2) ^ ((r & 7) << 4);
                *(__bf16*)(sm + byte) = (__bf16)acc[mf][nf][reg];
            }
    __syncthreads();

    // readout in fragment-tile order: 16 tiles x 64 lanes x 16B
    char* qb = qhatF + (size_t)blockIdx.x * 16384;
    #pragma unroll
    for (int it = 0; it < 4; ++it) {
        const int idx = it * 256 + tid;         // 0..1023
        const int tile = idx >> 6, l2 = idx & 63;
        const int s  = tile >> 1, qt = tile & 1;
        const int row = qt * 16 + (l2 & 15);
        const int k0  = s * 32 + (l2 >> 4) * 8;
        const int byte = (row * 512 + k0 * 2) ^ ((row & 7) << 4);
        bf16x8 hv = *(const bf16x8*)(sm + byte);
        const float rn = (toks[row] == 0) ? 0.f
                                          : 1.f / (sqrtf(ssq[row]) + 1e-9f);
        #pragma unroll
        for (int j = 0; j < 8; ++j) hv[j] = (__bf16)((float)hv[j] * rn);
        *(bf16x8*)(qb + tile * 1024 + l2 * 16) = hv;
    }
}

// ---------------------------------------------------------------------------
// Fused v10: 32 docs/block, 256 thr (4 waves). Coalesced qhatF tile loads in
// sims; algebraic RBF (4 exps); direct global atomics (no LDS red bounce).
// ---------------------------------------------------------------------------
__global__ __launch_bounds__(256) void knrm_fused2(
    const int* __restrict__ dtok,
    const float* __restrict__ dent,
    const char* __restrict__ Pp,
    const __bf16* __restrict__ Wep,
    const float* __restrict__ bias,
    const char* __restrict__ qhatF,
    float* __restrict__ ksum,    // [B, NK, QLEN]
    float* __restrict__ simsum)  // [B, QLEN]
{
    __shared__ __align__(16) char sm[16384 + 256];
    float* ssq  = (float*)(sm + 16384);          // [32]
    int*   toks = (int*)(sm + 16384 + 128);      // [32]

    const int tid = threadIdx.x;
    const int b   = blockIdx.y;
    const int d0  = blockIdx.x * 32;
    const int drow0 = b * DLEN + d0;
    const int w  = tid >> 6;     // 0..3 : col quarter (transform)
    const int l  = tid & 63;
    const int lr = l & 15;
    const int lg = l >> 4;

    if (tid < 32) { toks[tid] = dtok[drow0 + tid] + 1; ssq[tid] = 0.f; }

    // stage dent -> Ab bf16 [32][128] swz at sm[0..8K)
    #pragma unroll
    for (int u = 0; u < 4; ++u) {
        const int slot = u * 256 + tid;          // 0..1023
        const int r    = slot >> 5;
        const int c4   = (slot & 31) * 4;
        const f32x4 v = *(const f32x4*)(dent + (size_t)(drow0 + r) * ENT + c4);
        bf16x4 hv;
        #pragma unroll
        for (int c = 0; c < 4; ++c) hv[c] = (__bf16)v[c];
        *(bf16x4*)(sm + ((r * 256 + c4 * 2) ^ ((r & 7) << 4))) = hv;
    }
    __syncthreads();

    // early P gather (L3 latency hides under MFMA loop)
    bf16x4 pv[2][4];
    #pragma unroll
    for (int mf = 0; mf < 2; ++mf)
        #pragma unroll
        for (int reg = 0; reg < 4; ++reg) {
            const int doc = mf * 16 + lg * 4 + reg;
            pv[mf][reg] = *(const bf16x4*)(Pp +
                (size_t)toks[doc] * 512 + w * 128 + lr * 8);
        }

    f32x4 acc[2][4];
    #pragma unroll
    for (int mf = 0; mf < 2; ++mf)
        #pragma unroll
        for (int nf = 0; nf < 4; ++nf)
            acc[mf][nf] = (f32x4){0.f, 0.f, 0.f, 0.f};

    #pragma unroll
    for (int t = 0; t < 4; ++t) {
        bf16x8 a[2];
        #pragma unroll
        for (int mf = 0; mf < 2; ++mf) {
            const int row = mf * 16 + lr;
            a[mf] = *(const bf16x8*)(sm +
                ((row * 256 + t * 64 + lg * 16) ^ ((row & 7) << 4)));
        }
        bf16x8 wv[4];
        #pragma unroll
        for (int nf = 0; nf < 4; ++nf) {
            const int tile = t * 16 + w * 4 + nf;
            wv[nf] = *(const bf16x8*)((const char*)Wep + (size_t)tile * 1024 + l * 16);
        }
        #pragma unroll
        for (int mf = 0; mf < 2; ++mf)
            #pragma unroll
            for (int nf = 0; nf < 4; ++nf)
                acc[mf][nf] = __builtin_amdgcn_mfma_f32_16x16x32_bf16(
                    a[mf], wv[nf], acc[mf][nf], 0, 0, 0);
    }
    __syncthreads();   // Ab reads done; region reusable as T

    float bv[4];
    #pragma unroll
    for (int nf = 0; nf < 4; ++nf) bv[nf] = bias[w * 64 + nf * 16 + lr];
    float sq[2][4];
    #pragma unroll
    for (int mf = 0; mf < 2; ++mf)
        #pragma unroll
        for (int reg = 0; reg < 4; ++reg) {
            float s = 0.f;
            #pragma unroll
            for (int nf = 0; nf < 4; ++nf) {
                const float v = fmaxf(acc[mf][nf][reg] + (float)pv[mf][reg][nf]
                                      + bv[nf], 0.f);
                acc[mf][nf][reg] = v;
                s = fmaf(v, v, s);
            }
            sq[mf][reg] = s;
        }
    #pragma unroll
    for (int m = 1; m <= 8; m <<= 1)
        #pragma unroll
        for (int mf = 0; mf < 2; ++mf)
            #pragma unroll
            for (int reg = 0; reg < 4; ++reg)
                sq[mf][reg] += __shfl_xor(sq[mf][reg], m, 64);
    if (lr == 0) {
        #pragma unroll
        for (int mf = 0; mf < 2; ++mf)
            #pragma unroll
            for (int reg = 0; reg < 4; ++reg)
                atomicAdd(&ssq[mf * 16 + lg * 4 + reg], sq[mf][reg]);
    }
    // write T [doc][256] bf16: byte = doc*512 + (col*2 ^ ((doc&15)<<4))
    #pragma unroll
    for (int mf = 0; mf < 2; ++mf)
        #pragma unroll
        for (int nf = 0; nf < 4; ++nf)
            #pragma unroll
            for (int reg = 0; reg < 4; ++reg) {
                const int doc  = mf * 16 + lg * 4 + reg;
                const int col  = w * 64 + nf * 16 + lr;
                const int byte = doc * 512 + ((col * 2) ^ ((doc & 15) << 4));
                *(__bf16*)(sm + byte) = (__bf16)acc[mf][nf][reg];
            }
    __syncthreads();   // T + ssq visible

    // sims: wave -> dtile=w&1 (16 docs, M), qtile=w>>1 (16 q, N)
    const int dtile = w & 1, qtile = w >> 1;
    const int tdoc  = dtile * 16 + lr;
    const int q     = qtile * 16 + lr;
    const char* __restrict__ qb = qhatF + (size_t)b * 16384;
    f32x4 s0 = (f32x4){0.f, 0.f, 0.f, 0.f};
    #pragma unroll
    for (int s = 0; s < 8; ++s) {
        const bf16x8 ta = *(const bf16x8*)(sm +
            (tdoc * 512 + ((s * 64 + lg * 16) ^ ((tdoc & 15) << 4))));
        const bf16x8 qv = *(const bf16x8*)(qb + (s * 2 + qtile) * 1024 + l * 16);
        s0 = __builtin_amdgcn_mfma_f32_16x16x32_bf16(ta, qv, s0, 0, 0, 0);
    }

    // RBF (algebraic): kern_k = Ck * v5 * g^(k-5), v5=exp(-50s^2+10s), g=exp(20s)
    float kq[12];
    #pragma unroll
    for (int k = 0; k < 12; ++k) kq[k] = 0.f;
    #pragma unroll
    for (int reg = 0; reg < 4; ++reg) {
        const int doc = dtile * 16 + lg * 4 + reg;
        const float dnv = (toks[doc] == 0) ? 0.f
                                           : 1.f / (sqrtf(ssq[doc]) + 1e-9f);
        const float sv = s0[reg] * dnv;
        kq[11] += sv;
        const float v5 = __expf(fmaf(10.f, sv, -50.f * sv * sv));
        const float gU = __expf(20.f * sv);
        const float gD = __expf(-20.f * sv);
        float u = v5;
        kq[5] += u * 0.60653066f;
        u *= gD; kq[4] += u * 0.60653066f;
        u *= gD; kq[3] += u * 0.011108997f;
        u *= gD; kq[2] += u * 3.7266532e-06f;
        u *= gD; kq[1] += u * 2.2895532e-11f;
        u *= gD; kq[0] += u * 2.5767571e-18f;
        u = v5;
        u *= gU; kq[6] += u * 0.011108997f;
        u *= gU; kq[7] += u * 3.7266532e-06f;
        u *= gU; kq[8] += u * 2.2895532e-11f;
        u *= gU; kq[9] += u * 2.5767571e-18f;
        const float t10 = sv - 1.0f;
        kq[10] += __expf(-500000.f * t10 * t10);
    }
    #pragma unroll
    for (int m = 16; m <= 32; m <<= 1)
        #pragma unroll
        for (int k = 0; k < 12; ++k)
            kq[k] += __shfl_xor(kq[k], m, 64);
    if (lg == 0) {
        #pragma unroll
        for (int k = 0; k < NK; ++k)
            atomicAdd(&ksum[((size_t)b * NK + k) * QLEN + q], kq[k]);
        atomicAdd(&simsum[b * QLEN + q], kq[11]);
    }
}

// ---------------------------------------------------------------------------
__global__ __launch_bounds__(384) void knrm_final(
    const float* __restrict__ ksum,
    const float* __restrict__ simsum,
    const float* __restrict__ Wc, const float* __restrict__ bc,
    float* __restrict__ out)
{
    __shared__ float redq[NK][QLEN];
    __shared__ float res[NK];
    const int b = blockIdx.x;
    const int t = threadIdx.x;
    if (t < NK * QLEN) {
        const int k = t >> 5;
        const int q = t & 31;
        const float ms = simsum[b * QLEN + q];
        redq[k][q] = (ms != 0.0f)
            ? logf(ksum[((size_t)b * NK + k) * QLEN + q] + 1e-6f)
            : 0.0f;
    }
    __syncthreads();
    if (t < NK) {
        float s = 0.f;
        for (int q = 0; q < QLEN; ++q) s += redq[t][q];
        res[t] = s;
    }
    __syncthreads();
    if (t == 0) {
        float s = bc[0];
        for (int k = 0; k < NK; ++k) s += res[k] * Wc[k];
        out[b] = s;
    }
}

// ---------------------------------------------------------------------------
extern "C" void kernel_launch(void* const* d_in, const int* in_sizes, int n_in,
                              void* d_out, int out_size, void* d_ws, size_t ws_size,
                              hipStream_t stream)
{
    (void)in_sizes; (void)n_in; (void)out_size; (void)ws_size;
    const int*   qtok = (const int*)d_in[0];
    const int*   dtok = (const int*)d_in[1];
    const float* qent = (const float*)d_in[2];
    const float* dent = (const float*)d_in[3];
    const float* emb  = (const float*)d_in[4];
    const float* Wt   = (const float*)d_in[5];
    const float* bt   = (const float*)d_in[6];
    const float* We   = (const float*)d_in[7];
    const float* be   = (const float*)d_in[8];
    const float* Wc   = (const float*)d_in[9];
    const float* bc   = (const float*)d_in[10];
    float* out = (float*)d_out;

    char* ws = (char*)d_ws;
    const size_t off_qhat = 0;                               // 1,048,576
    const size_t off_Wtp  = off_qhat + 1048576;              //   163,840
    const size_t off_Wep  = off_Wtp  + 163840;               //    65,536
    const size_t off_bias = off_Wep  + 65536;                //     1,024
    const size_t off_ksum = off_bias + 1024;                 //    90,112
    const size_t off_sim  = off_ksum + 90112;                //     8,192
    const size_t off_P    = off_sim  + 8192;                 // 25,600,000

    char*   qhatF = ws + off_qhat;
    __bf16* Wtp   = (__bf16*)(ws + off_Wtp);
    __bf16* Wep   = (__bf16*)(ws + off_Wep);
    float*  bias  = (float*)(ws + off_bias);
    float*  ksum  = (float*)(ws + off_ksum);
    float*  simsum= (float*)(ws + off_sim);
    char*   P     = ws + off_P;

    hipMemsetAsync(ksum, 0, (size_t)(90112 + 8192), stream);

    knrm_wpack<<<dim3(56), dim3(256), 0, stream>>>(Wt, We, bt, be, Wtp, Wep, bias);
    knrm_pgemm<<<dim3((VOCAB + 63) / 64), dim3(256), 0, stream>>>(emb, Wtp, P);
    knrm_qtrans<<<dim3(64), dim3(256), 0, stream>>>(
        qtok, qent, P, Wep, bias, qhatF);
    knrm_fused2<<<dim3(DLEN / 32, B_), dim3(256), 0, stream>>>(
        dtok, dent, P, Wep, bias, qhatF, ksum, simsum);
    knrm_final<<<dim3(B_), dim3(384), 0, stream>>>(ksum, simsum, Wc, bc, out);
}